// Round 10
// baseline (236.870 us; speedup 1.0000x reference)
//
#include <hip/hip_runtime.h>
#include <hip/hip_bf16.h>

// Problem constants (from reference)
#define N_NODES 50000
#define N_EDGES 800000
#define EP (N_EDGES + N_NODES)   // edges incl. self loops = 850000
#define IN_C 128
#define HID 32
#define OUT_C 64
#define HEADS 4
#define NEG_SLOPE 0.2f

#define NPB 128                          // nodes per bucket (power of 2)
#define K_BUCKETS ((N_NODES + NPB - 1) / NPB)   // 391

typedef unsigned int uint32;

__device__ __forceinline__ float bf_lo(uint32 u) { return __uint_as_float(u << 16); }
__device__ __forceinline__ float bf_hi(uint32 u) { return __uint_as_float(u & 0xffff0000u); }
// round-to-nearest-even f32 -> bf16 (no NaN inputs here)
__device__ __forceinline__ uint32 f2bf(float f) {
    uint32 u = __float_as_uint(f);
    return (u + 0x7fffu + ((u >> 16) & 1u)) >> 16;
}
__device__ __forceinline__ uint32 pack_bf2(float a, float b) {
    return f2bf(a) | (f2bf(b) << 16);
}

// ---------- init: zero bucket counts + attention vectors + packed weights -----
// wals/wald[h*32+k] = sum_d Wg[k, h*32+d] * ag[h, d]
// wgp: bf16-packed Wg' for gat epilogue. uint2 idx (j4*32+d): channels
//      c=4j4+e, W'[c][d] = Wg[(c&31)*128 + (c>>5)*32 + d]
// w2p: bf16-packed W2 for gcn2 epilogue. uint2 idx (k4*64+d): rows 4k4+e.
__global__ __launch_bounds__(512) void k_init2(int* __restrict__ gcnt,
                                               const float* __restrict__ Wg,
                                               const float* __restrict__ ags,
                                               const float* __restrict__ agd,
                                               float* __restrict__ wals,
                                               float* __restrict__ wald,
                                               const float* __restrict__ W2,
                                               uint32* __restrict__ wgp,
                                               uint32* __restrict__ w2p) {
    int t = threadIdx.x;
    if (t < K_BUCKETS + 1) gcnt[t] = 0;
    if (t < 256) {
        int c = t & 127;
        int h = c >> 5, k = c & 31;
        const float* a = (t < 128) ? ags : agd;
        float acc = 0.f;
#pragma unroll
        for (int d = 0; d < 32; d++) acc += Wg[k * 128 + h * 32 + d] * a[h * 32 + d];
        if (t < 128) wals[c] = acc; else wald[c] = acc;
    }
    for (int i = t; i < 2048; i += 512) {
        int j4 = i >> 6, d = (i >> 1) & 31, pp = i & 1;
        int c0 = 4 * j4 + 2 * pp, c1 = c0 + 1;
        float a = Wg[(c0 & 31) * 128 + (c0 >> 5) * 32 + d];
        float b = Wg[(c1 & 31) * 128 + (c1 >> 5) * 32 + d];
        wgp[i] = pack_bf2(a, b);
    }
    for (int i = t; i < 1024; i += 512) {
        int k4 = i >> 7, d = (i >> 1) & 63, pp = i & 1;
        int r0 = 4 * k4 + 2 * pp, r1 = r0 + 1;
        w2p[i] = pack_bf2(W2[r0 * 64 + d], W2[r1 * 64 + d]);
    }
}

// ---------- CSR build via two-level bucket sort ----------

__global__ __launch_bounds__(256) void k_bcount(const int* __restrict__ ei,
                                                int* __restrict__ gcnt) {
    __shared__ int h[K_BUCKETS];
    int t = threadIdx.x;
    for (int i = t; i < K_BUCKETS; i += 256) h[i] = 0;
    __syncthreads();
    int base = blockIdx.x * 4096;
    int dd[16];
#pragma unroll
    for (int k = 0; k < 16; k++) {
        int e = base + k * 256 + t;
        dd[k] = (e < N_EDGES) ? ei[N_EDGES + e] : -1;
    }
#pragma unroll
    for (int k = 0; k < 16; k++)
        if (dd[k] >= 0) atomicAdd(&h[dd[k] >> 7], 1);
    __syncthreads();
    for (int i = t; i < K_BUCKETS; i += 256)
        if (h[i]) atomicAdd(&gcnt[i], h[i]);
}

__global__ __launch_bounds__(512) void k_bscan(const int* __restrict__ gcnt,
                                               int* __restrict__ gbase,
                                               int* __restrict__ gcursor) {
    __shared__ int sd[512];
    int t = threadIdx.x;
    int v = (t < K_BUCKETS) ? gcnt[t] : 0;
    sd[t] = v;
    __syncthreads();
    for (int off = 1; off < 512; off <<= 1) {
        int x = (t >= off) ? sd[t - off] : 0;
        __syncthreads();
        sd[t] += x;
        __syncthreads();
    }
    if (t < K_BUCKETS) {
        int excl = sd[t] - v;
        gbase[t] = excl;
        gcursor[t] = excl;
    }
    if (t == 0) gbase[K_BUCKETS] = sd[K_BUCKETS - 1];
}

__global__ __launch_bounds__(256) void k_bucket(const int* __restrict__ ei,
                                                int* __restrict__ gcursor,
                                                uint32* __restrict__ gpairs) {
    __shared__ int cnt[K_BUCKETS];
    __shared__ int bas[K_BUCKETS];
    int t = threadIdx.x;
    for (int i = t; i < K_BUCKETS; i += 256) cnt[i] = 0;
    __syncthreads();
    int base = blockIdx.x * 2048;
    int ss[8], dd[8], ml[8];
#pragma unroll
    for (int k = 0; k < 8; k++) {
        int e = base + k * 256 + t;
        ss[k] = (e < N_EDGES) ? ei[e] : -1;
        dd[k] = (e < N_EDGES) ? ei[N_EDGES + e] : 0;
    }
#pragma unroll
    for (int k = 0; k < 8; k++)
        if (ss[k] >= 0) ml[k] = atomicAdd(&cnt[dd[k] >> 7], 1);
    __syncthreads();
    for (int i = t; i < K_BUCKETS; i += 256)
        bas[i] = cnt[i] ? atomicAdd(&gcursor[i], cnt[i]) : 0;
    __syncthreads();
#pragma unroll
    for (int k = 0; k < 8; k++)
        if (ss[k] >= 0)
            gpairs[bas[dd[k] >> 7] + ml[k]] = ((uint32)ss[k] << 7) | (uint32)(dd[k] & 127);
}

__global__ __launch_bounds__(256) void k_node(const uint32* __restrict__ gpairs,
                                              const int* __restrict__ gbase,
                                              int* __restrict__ offs,
                                              float* __restrict__ dinv,
                                              int* __restrict__ srcs) {
    __shared__ int cnt[NPB];
    __shared__ int scn[NPB];
    __shared__ int cur[NPB];
    int t = threadIdx.x;
    int b = blockIdx.x;
    int lo = b << 7;
    int nn = N_NODES - lo; if (nn > NPB) nn = NPB;
    int pb = gbase[b], pe = gbase[b + 1];
    if (t < NPB) cnt[t] = 0;
    __syncthreads();
    for (int i = pb + t; i < pe; i += 256)
        atomicAdd(&cnt[gpairs[i] & 127], 1);
    __syncthreads();
    if (t < NPB) scn[t] = cnt[t];
    __syncthreads();
    for (int off = 1; off < NPB; off <<= 1) {
        int x = 0;
        if (t >= off && t < NPB) x = scn[t - off];
        __syncthreads();
        if (t < NPB) scn[t] += x;
        __syncthreads();
    }
    if (t < nn) {
        int excl = scn[t] - cnt[t];
        int o = pb + excl + lo + t;
        offs[lo + t] = o;
        cur[t] = o;
        dinv[lo + t] = rsqrtf((float)(cnt[t] + 1));
        srcs[pb + scn[t] + lo + t] = lo + t;   // self-loop at last slot
    }
    if (b == K_BUCKETS - 1 && t == 0) offs[N_NODES] = pe + N_NODES;
    __syncthreads();
    for (int i = pb + t; i < pe; i += 256) {
        uint32 u = gpairs[i];
        int pos = atomicAdd(&cur[u & 127], 1);
        srcs[pos] = (int)(u >> 7);
    }
}

// ---------- GCN1: xw1 = bf16( (x @ W1) * dinv[row] ), float2-LDS weights ------
__global__ __launch_bounds__(256) void k_gemm1(const float* __restrict__ x,
                                               const float* __restrict__ W1,
                                               const float* __restrict__ dinv,
                                               uint32* __restrict__ xw1) {
    __shared__ float wl[IN_C * HID];   // as float2[k2][f]
    __shared__ float xl[8 * IN_C];
    int t = threadIdx.x;
    for (int i = t; i < IN_C * HID; i += 256) {
        int k = i >> 5, f = i & 31;
        wl[(k >> 1) * 64 + f * 2 + (k & 1)] = W1[i];
    }
    int nb = blockIdx.x * 8;
    const float4* x4 = (const float4*)(x + (size_t)nb * IN_C);
    ((float4*)xl)[t] = x4[t];
    __syncthreads();
    int g = t >> 5, f = t & 31;
    const float2* xr = (const float2*)(xl + g * IN_C);
    const float2* wp = (const float2*)wl;
    float acc = 0.f;
#pragma unroll 16
    for (int k2 = 0; k2 < 64; k2++) {
        float2 xv = xr[k2];
        float2 wv = wp[k2 * 32 + f];
        acc += xv.x * wv.x + xv.y * wv.y;
    }
    float v = acc * dinv[nb + g];
    float vn = __shfl_xor(v, 1, 64);
    if ((f & 1) == 0) xw1[(size_t)(nb + g) * 16 + (f >> 1)] = pack_bf2(v, vn);
}

// ---------- GCN1 aggregate -> h1s (bf16, post-relu) + als/ald ----------
__global__ __launch_bounds__(256) void k_gather1(const uint32* __restrict__ xw1,
                                                 const int* __restrict__ offs,
                                                 const int* __restrict__ srcs,
                                                 const float* __restrict__ dinv,
                                                 const float* __restrict__ b1,
                                                 const float* __restrict__ wals,
                                                 const float* __restrict__ wald,
                                                 uint32* __restrict__ h1s,
                                                 float* __restrict__ als,
                                                 float* __restrict__ ald) {
    int t = threadIdx.x;
    int l16 = t & 15;
    int n = blockIdx.x * 16 + (t >> 4);
    int s0 = offs[n], s1 = offs[n + 1];
    const uint32* xc = xw1 + l16;
    float a0 = 0.f, a1 = 0.f, a2 = 0.f, a3 = 0.f;
    int j = s0;
    for (; j + 1 < s1; j += 2) {
        uint32 uA = xc[(size_t)srcs[j] * 16];
        uint32 uB = xc[(size_t)srcs[j + 1] * 16];
        a0 += bf_lo(uA); a1 += bf_hi(uA);
        a2 += bf_lo(uB); a3 += bf_hi(uB);
    }
    if (j < s1) {
        uint32 uA = xc[(size_t)srcs[j] * 16];
        a0 += bf_lo(uA); a1 += bf_hi(uA);
    }
    float dn = dinv[n];
    float2 b = ((const float2*)b1)[l16];
    float vx = (a0 + a2) * dn + b.x;
    float vy = (a1 + a3) * dn + b.y;
    vx = vx > 0.f ? vx : 0.f;
    vy = vy > 0.f ? vy : 0.f;
    h1s[(size_t)n * 16 + l16] = pack_bf2(vx, vy);

    float ps0, ps1, ps2, ps3, pd0, pd1, pd2, pd3;
    {
        float2 w0 = ((const float2*)wals)[0 * 16 + l16];
        float2 w1 = ((const float2*)wals)[1 * 16 + l16];
        float2 w2 = ((const float2*)wals)[2 * 16 + l16];
        float2 w3 = ((const float2*)wals)[3 * 16 + l16];
        ps0 = vx * w0.x + vy * w0.y;
        ps1 = vx * w1.x + vy * w1.y;
        ps2 = vx * w2.x + vy * w2.y;
        ps3 = vx * w3.x + vy * w3.y;
        float2 u0 = ((const float2*)wald)[0 * 16 + l16];
        float2 u1 = ((const float2*)wald)[1 * 16 + l16];
        float2 u2 = ((const float2*)wald)[2 * 16 + l16];
        float2 u3 = ((const float2*)wald)[3 * 16 + l16];
        pd0 = vx * u0.x + vy * u0.y;
        pd1 = vx * u1.x + vy * u1.y;
        pd2 = vx * u2.x + vy * u2.y;
        pd3 = vx * u3.x + vy * u3.y;
    }
#pragma unroll
    for (int m = 1; m < 16; m <<= 1) {
        ps0 += __shfl_xor(ps0, m, 16); ps1 += __shfl_xor(ps1, m, 16);
        ps2 += __shfl_xor(ps2, m, 16); ps3 += __shfl_xor(ps3, m, 16);
        pd0 += __shfl_xor(pd0, m, 16); pd1 += __shfl_xor(pd1, m, 16);
        pd2 += __shfl_xor(pd2, m, 16); pd3 += __shfl_xor(pd3, m, 16);
    }
    if (l16 == 0) {
        als[n * 4 + 0] = ps0; als[n * 4 + 1] = ps1;
        als[n * 4 + 2] = ps2; als[n * 4 + 3] = ps3;
        ald[n * 4 + 0] = pd0; ald[n * 4 + 1] = pd1;
        ald[n * 4 + 2] = pd2; ald[n * 4 + 3] = pd3;
    }
}

// ---------- Fused GAT: edge aggregate in h1-space + 128->32 post-GEMM ---------
// 8 nodes x 32 lanes. Edge loop as before; per-node 128-dim g staged in LDS as
// bf16 pairs (norm*0.25 folded); epilogue vs bf16-packed Wg' (8 KB LDS).
// Epilogue DS bytes halved vs fp32 (DS pipe is bytes-bound, m134).
__global__ __launch_bounds__(256) void k_gat_agg(const uint32* __restrict__ h1s,
                                                 const float* __restrict__ als,
                                                 const float* __restrict__ ald,
                                                 const int* __restrict__ offs,
                                                 const int* __restrict__ srcs,
                                                 const uint32* __restrict__ wgp,
                                                 const float* __restrict__ bg,
                                                 const float* __restrict__ dinv,
                                                 uint32* __restrict__ h2s) {
    __shared__ __align__(16) uint32 wl[2048];   // packed Wg': 8 KB
    __shared__ __align__(16) uint32 gl[8][64];  // packed g: 2 KB
    int t = threadIdx.x;
    {   // stage packed weights: 2 x b128 per thread, coalesced
        const uint4* src4 = (const uint4*)wgp;
        uint4* dst4 = (uint4*)wl;
        dst4[t] = src4[t];
        dst4[256 + t] = src4[256 + t];
    }

    int l32 = t & 31;
    int hb = t & 32;             // wave-half base for shuffles
    int g8 = t >> 5;             // node slot in block
    int n = blockIdx.x * 8 + g8;
    int h = l32 >> 3, e8 = l32 & 7;
    int l16 = l32 & 15;
    int h16 = (l32 >> 4) & 1;    // edge parity for gather half
    int s0 = offs[n], s1 = offs[n + 1];
    float ad = ald[n * 4 + h];
    const uint32* rowp = h1s + l16;

    float g00 = 0.f, g01 = 0.f, g10 = 0.f, g11 = 0.f;
    float g20 = 0.f, g21 = 0.f, g30 = 0.f, g31 = 0.f;
    float ssum = 0.f;
    for (int base = s0; base < s1; base += 8) {
        int jj = base + e8;
        int sA = 0; float wt = 0.f;
        if (jj < s1) {
            sA = srcs[jj];
            float l = als[sA * 4 + h] + ad;
            l = l > 0.f ? l : NEG_SLOPE * l;
            wt = __expf(l);
        }
        ssum += wt;
        int cnt = s1 - base; if (cnt > 8) cnt = 8;
#pragma unroll
        for (int q = 0; q < 8; q += 2) {
            int eq = q + h16;
            int   sq = __shfl(sA, hb + eq, 64);
            float w0 = __shfl(wt, hb + eq, 64);
            float w1 = __shfl(wt, hb + 8 + eq, 64);
            float w2 = __shfl(wt, hb + 16 + eq, 64);
            float w3 = __shfl(wt, hb + 24 + eq, 64);
            if (eq < cnt) {
                uint32 u = rowp[(size_t)sq * 16];
                float flo = bf_lo(u), fhi = bf_hi(u);
                g00 += w0 * flo; g01 += w0 * fhi;
                g10 += w1 * flo; g11 += w1 * fhi;
                g20 += w2 * flo; g21 += w2 * fhi;
                g30 += w3 * flo; g31 += w3 * fhi;
            }
        }
    }
    ssum += __shfl_xor(ssum, 1, 64);
    ssum += __shfl_xor(ssum, 2, 64);
    ssum += __shfl_xor(ssum, 4, 64);
    float inv = 0.25f / ssum;    // head-mean folded
    float inv0 = __shfl(inv, hb + 0, 64);
    float inv1 = __shfl(inv, hb + 8, 64);
    float inv2 = __shfl(inv, hb + 16, 64);
    float inv3 = __shfl(inv, hb + 24, 64);
    g00 += __shfl_xor(g00, 16, 64); g01 += __shfl_xor(g01, 16, 64);
    g10 += __shfl_xor(g10, 16, 64); g11 += __shfl_xor(g11, 16, 64);
    g20 += __shfl_xor(g20, 16, 64); g21 += __shfl_xor(g21, 16, 64);
    g30 += __shfl_xor(g30, 16, 64); g31 += __shfl_xor(g31, 16, 64);
    if (l32 < 16) {
        // c2 = h*16 + l16 covers channels (2c2, 2c2+1) = (h*32+2l16, +1)
        gl[g8][0 * 16 + l16] = pack_bf2(g00 * inv0, g01 * inv0);
        gl[g8][1 * 16 + l16] = pack_bf2(g10 * inv1, g11 * inv1);
        gl[g8][2 * 16 + l16] = pack_bf2(g20 * inv2, g21 * inv2);
        gl[g8][3 * 16 + l16] = pack_bf2(g30 * inv3, g31 * inv3);
    }
    __syncthreads();
    // epilogue: d = l32; acc = sum_c g[c] * Wg'[c][d], 4 channels per iter
    const uint2* gv = (const uint2*)gl[g8];
    const uint2* wp = (const uint2*)wl;
    int d = l32;
    float acc = 0.f;
#pragma unroll 8
    for (int j4 = 0; j4 < 32; j4++) {
        uint2 gg = gv[j4];            // channels 4j4..4j4+3 (broadcast)
        uint2 ww = wp[j4 * 32 + d];
        acc += bf_lo(gg.x) * bf_lo(ww.x) + bf_hi(gg.x) * bf_hi(ww.x)
             + bf_lo(gg.y) * bf_lo(ww.y) + bf_hi(gg.y) * bf_hi(ww.y);
    }
    float v = acc + bg[d];
    v = v > 0.f ? v : 0.f;
    v *= dinv[n];
    float vn = __shfl_xor(v, 1, 64);
    if ((d & 1) == 0) h2s[(size_t)n * 16 + (d >> 1)] = pack_bf2(v, vn);
}

// ---------- Fused GCN2: edge aggregate in h2-space + 32->64 output GEMM -------
// 16 nodes x 16 lanes; g2 staged bf16; epilogue vs bf16-packed W2 (4 KB LDS).
__global__ __launch_bounds__(256) void k_gather2(const uint32* __restrict__ h2s,
                                                 const int* __restrict__ offs,
                                                 const int* __restrict__ srcs,
                                                 const uint32* __restrict__ w2p,
                                                 const float* __restrict__ dinv,
                                                 const float* __restrict__ b2,
                                                 float* __restrict__ out) {
    __shared__ __align__(16) uint32 wl[1024];    // packed W2: 4 KB
    __shared__ __align__(16) uint32 gbf[16][16]; // packed g2: 1 KB
    int t = threadIdx.x;
    ((uint4*)wl)[t] = ((const uint4*)w2p)[t];    // 1 b128 per thread

    int l16 = t & 15;
    int g16 = t >> 4;
    int n = blockIdx.x * 16 + g16;
    int s0 = offs[n], s1 = offs[n + 1];
    const uint32* xc = h2s + l16;
    float a0 = 0.f, a1 = 0.f, a2 = 0.f, a3 = 0.f;
    int j = s0;
    for (; j + 1 < s1; j += 2) {
        uint32 uA = xc[(size_t)srcs[j] * 16];
        uint32 uB = xc[(size_t)srcs[j + 1] * 16];
        a0 += bf_lo(uA); a1 += bf_hi(uA);
        a2 += bf_lo(uB); a3 += bf_hi(uB);
    }
    if (j < s1) {
        uint32 uA = xc[(size_t)srcs[j] * 16];
        a0 += bf_lo(uA); a1 += bf_hi(uA);
    }
    gbf[g16][l16] = pack_bf2(a0 + a2, a1 + a3);
    __syncthreads();
    // epilogue: 4 outputs per thread, d = l16 + 16*i; 4 k-rows per iter
    const uint2* gv = (const uint2*)gbf[g16];
    const uint2* wp = (const uint2*)wl;
    float dn = dinv[n];
    float acc0 = 0.f, acc1 = 0.f, acc2 = 0.f, acc3 = 0.f;
#pragma unroll
    for (int k4 = 0; k4 < 8; k4++) {
        uint2 gg = gv[k4];            // channels 4k4..4k4+3 (broadcast)
        float gx = bf_lo(gg.x), gy = bf_hi(gg.x);
        float gz = bf_lo(gg.y), gw = bf_hi(gg.y);
        uint2 w0 = wp[k4 * 64 + l16];
        uint2 w1 = wp[k4 * 64 + l16 + 16];
        uint2 w2 = wp[k4 * 64 + l16 + 32];
        uint2 w3 = wp[k4 * 64 + l16 + 48];
        acc0 += gx * bf_lo(w0.x) + gy * bf_hi(w0.x) + gz * bf_lo(w0.y) + gw * bf_hi(w0.y);
        acc1 += gx * bf_lo(w1.x) + gy * bf_hi(w1.x) + gz * bf_lo(w1.y) + gw * bf_hi(w1.y);
        acc2 += gx * bf_lo(w2.x) + gy * bf_hi(w2.x) + gz * bf_lo(w2.y) + gw * bf_hi(w2.y);
        acc3 += gx * bf_lo(w3.x) + gy * bf_hi(w3.x) + gz * bf_lo(w3.y) + gw * bf_hi(w3.y);
    }
    float* op = out + (size_t)n * OUT_C;
    op[l16]      = acc0 * dn + b2[l16];
    op[l16 + 16] = acc1 * dn + b2[l16 + 16];
    op[l16 + 32] = acc2 * dn + b2[l16 + 32];
    op[l16 + 48] = acc3 * dn + b2[l16 + 48];
}

extern "C" void kernel_launch(void* const* d_in, const int* in_sizes, int n_in,
                              void* d_out, int out_size, void* d_ws, size_t ws_size,
                              hipStream_t stream) {
    const float* x   = (const float*)d_in[0];
    const int*   ei  = (const int*)d_in[1];   // int64 in reference -> int32 from harness
    const float* W1  = (const float*)d_in[2];
    const float* b1  = (const float*)d_in[3];
    const float* Wg  = (const float*)d_in[4];
    const float* ags = (const float*)d_in[5];
    const float* agd = (const float*)d_in[6];
    const float* bg  = (const float*)d_in[7];
    const float* W2  = (const float*)d_in[8];
    const float* b2  = (const float*)d_in[9];
    float* out = (float*)d_out;

    char* p = (char*)d_ws;
    auto alloc = [&](size_t bytes) -> void* {
        void* r = (void*)p;
        p += (bytes + 255) & ~(size_t)255;
        return r;
    };
    float*  dinv    = (float*)alloc((size_t)N_NODES * 4);
    int*    offs    = (int*)  alloc((size_t)(N_NODES + 1) * 4);
    int*    gcnt    = (int*)  alloc((size_t)(K_BUCKETS + 1) * 4);
    int*    gbase   = (int*)  alloc((size_t)(K_BUCKETS + 1) * 4);
    int*    gcursor = (int*)  alloc((size_t)(K_BUCKETS + 1) * 4);
    int*    srcs    = (int*)  alloc((size_t)EP * 4);
    uint32* gpairs  = (uint32*)alloc((size_t)N_EDGES * 4);
    uint32* xw1     = (uint32*)alloc((size_t)N_NODES * 16 * 4);
    uint32* h1s     = (uint32*)alloc((size_t)N_NODES * 16 * 4);
    float*  als     = (float*)alloc((size_t)N_NODES * HEADS * 4);
    float*  ald     = (float*)alloc((size_t)N_NODES * HEADS * 4);
    float*  wals    = (float*)alloc(128 * 4);
    float*  wald    = (float*)alloc(128 * 4);
    uint32* wgp     = (uint32*)alloc(2048 * 4);
    uint32* w2p     = (uint32*)alloc(1024 * 4);
    uint32* h2s     = (uint32*)alloc((size_t)N_NODES * 16 * 4);

    // init + CSR build (two-level bucket sort)
    k_init2<<<1, 512, 0, stream>>>(gcnt, Wg, ags, agd, wals, wald, W2, wgp, w2p);
    k_bcount<<<(N_EDGES + 4095) / 4096, 256, 0, stream>>>(ei, gcnt);
    k_bscan<<<1, 512, 0, stream>>>(gcnt, gbase, gcursor);
    k_bucket<<<(N_EDGES + 2047) / 2048, 256, 0, stream>>>(ei, gcursor, gpairs);
    k_node<<<K_BUCKETS, 256, 0, stream>>>(gpairs, gbase, offs, dinv, srcs);

    // GCN1
    k_gemm1<<<N_NODES / 8, 256, 0, stream>>>(x, W1, dinv, xw1);
    k_gather1<<<N_NODES / 16, 256, 0, stream>>>(xw1, offs, srcs, dinv, b1,
                                                wals, wald, h1s, als, ald);

    // GAT: edge aggregate + fused post-GEMM (bf16 epilogue)
    k_gat_agg<<<N_NODES / 8, 256, 0, stream>>>(h1s, als, ald, offs, srcs,
                                               wgp, bg, dinv, h2s);

    // GCN2: edge aggregate + fused output GEMM (bf16 epilogue)
    k_gather2<<<N_NODES / 16, 256, 0, stream>>>(h2s, offs, srcs, w2p, dinv, b2, out);
}

// Round 11
// 236.171 us; speedup vs baseline: 1.0030x; 1.0030x over previous
//
#include <hip/hip_runtime.h>
#include <hip/hip_bf16.h>

// Problem constants (from reference)
#define N_NODES 50000
#define N_EDGES 800000
#define EP (N_EDGES + N_NODES)   // edges incl. self loops = 850000
#define IN_C 128
#define HID 32
#define OUT_C 64
#define HEADS 4
#define NEG_SLOPE 0.2f

#define NPB 128                          // nodes per bucket (power of 2)
#define K_BUCKETS ((N_NODES + NPB - 1) / NPB)   // 391

typedef unsigned int uint32;

__device__ __forceinline__ float bf_lo(uint32 u) { return __uint_as_float(u << 16); }
__device__ __forceinline__ float bf_hi(uint32 u) { return __uint_as_float(u & 0xffff0000u); }
// round-to-nearest-even f32 -> bf16 (no NaN inputs here)
__device__ __forceinline__ uint32 f2bf(float f) {
    uint32 u = __float_as_uint(f);
    return (u + 0x7fffu + ((u >> 16) & 1u)) >> 16;
}
__device__ __forceinline__ uint32 pack_bf2(float a, float b) {
    return f2bf(a) | (f2bf(b) << 16);
}

// ---------- init: zero bucket counts + attention vectors + packed weights -----
__global__ __launch_bounds__(512) void k_init2(int* __restrict__ gcnt,
                                               const float* __restrict__ Wg,
                                               const float* __restrict__ ags,
                                               const float* __restrict__ agd,
                                               float* __restrict__ wals,
                                               float* __restrict__ wald,
                                               const float* __restrict__ W2,
                                               uint32* __restrict__ wgp,
                                               uint32* __restrict__ w2p) {
    int t = threadIdx.x;
    if (t < K_BUCKETS + 1) gcnt[t] = 0;
    if (t < 256) {
        int c = t & 127;
        int h = c >> 5, k = c & 31;
        const float* a = (t < 128) ? ags : agd;
        float acc = 0.f;
#pragma unroll
        for (int d = 0; d < 32; d++) acc += Wg[k * 128 + h * 32 + d] * a[h * 32 + d];
        if (t < 128) wals[c] = acc; else wald[c] = acc;
    }
    for (int i = t; i < 2048; i += 512) {
        int j4 = i >> 6, d = (i >> 1) & 31, pp = i & 1;
        int c0 = 4 * j4 + 2 * pp, c1 = c0 + 1;
        float a = Wg[(c0 & 31) * 128 + (c0 >> 5) * 32 + d];
        float b = Wg[(c1 & 31) * 128 + (c1 >> 5) * 32 + d];
        wgp[i] = pack_bf2(a, b);
    }
    for (int i = t; i < 1024; i += 512) {
        int k4 = i >> 7, d = (i >> 1) & 63, pp = i & 1;
        int r0 = 4 * k4 + 2 * pp, r1 = r0 + 1;
        w2p[i] = pack_bf2(W2[r0 * 64 + d], W2[r1 * 64 + d]);
    }
}

// ---------- CSR build via two-level bucket sort ----------

__global__ __launch_bounds__(256) void k_bcount(const int* __restrict__ ei,
                                                int* __restrict__ gcnt) {
    __shared__ int h[K_BUCKETS];
    int t = threadIdx.x;
    for (int i = t; i < K_BUCKETS; i += 256) h[i] = 0;
    __syncthreads();
    int base = blockIdx.x * 4096;
    int dd[16];
#pragma unroll
    for (int k = 0; k < 16; k++) {
        int e = base + k * 256 + t;
        dd[k] = (e < N_EDGES) ? ei[N_EDGES + e] : -1;
    }
#pragma unroll
    for (int k = 0; k < 16; k++)
        if (dd[k] >= 0) atomicAdd(&h[dd[k] >> 7], 1);
    __syncthreads();
    for (int i = t; i < K_BUCKETS; i += 256)
        if (h[i]) atomicAdd(&gcnt[i], h[i]);
}

__global__ __launch_bounds__(512) void k_bscan(const int* __restrict__ gcnt,
                                               int* __restrict__ gbase,
                                               int* __restrict__ gcursor) {
    __shared__ int sd[512];
    int t = threadIdx.x;
    int v = (t < K_BUCKETS) ? gcnt[t] : 0;
    sd[t] = v;
    __syncthreads();
    for (int off = 1; off < 512; off <<= 1) {
        int x = (t >= off) ? sd[t - off] : 0;
        __syncthreads();
        sd[t] += x;
        __syncthreads();
    }
    if (t < K_BUCKETS) {
        int excl = sd[t] - v;
        gbase[t] = excl;
        gcursor[t] = excl;
    }
    if (t == 0) gbase[K_BUCKETS] = sd[K_BUCKETS - 1];
}

__global__ __launch_bounds__(256) void k_bucket(const int* __restrict__ ei,
                                                int* __restrict__ gcursor,
                                                uint32* __restrict__ gpairs) {
    __shared__ int cnt[K_BUCKETS];
    __shared__ int bas[K_BUCKETS];
    int t = threadIdx.x;
    for (int i = t; i < K_BUCKETS; i += 256) cnt[i] = 0;
    __syncthreads();
    int base = blockIdx.x * 2048;
    int ss[8], dd[8], ml[8];
#pragma unroll
    for (int k = 0; k < 8; k++) {
        int e = base + k * 256 + t;
        ss[k] = (e < N_EDGES) ? ei[e] : -1;
        dd[k] = (e < N_EDGES) ? ei[N_EDGES + e] : 0;
    }
#pragma unroll
    for (int k = 0; k < 8; k++)
        if (ss[k] >= 0) ml[k] = atomicAdd(&cnt[dd[k] >> 7], 1);
    __syncthreads();
    for (int i = t; i < K_BUCKETS; i += 256)
        bas[i] = cnt[i] ? atomicAdd(&gcursor[i], cnt[i]) : 0;
    __syncthreads();
#pragma unroll
    for (int k = 0; k < 8; k++)
        if (ss[k] >= 0)
            gpairs[bas[dd[k] >> 7] + ml[k]] = ((uint32)ss[k] << 7) | (uint32)(dd[k] & 127);
}

__global__ __launch_bounds__(256) void k_node(const uint32* __restrict__ gpairs,
                                              const int* __restrict__ gbase,
                                              int* __restrict__ offs,
                                              float* __restrict__ dinv,
                                              int* __restrict__ srcs) {
    __shared__ int cnt[NPB];
    __shared__ int scn[NPB];
    __shared__ int cur[NPB];
    int t = threadIdx.x;
    int b = blockIdx.x;
    int lo = b << 7;
    int nn = N_NODES - lo; if (nn > NPB) nn = NPB;
    int pb = gbase[b], pe = gbase[b + 1];
    if (t < NPB) cnt[t] = 0;
    __syncthreads();
    for (int i = pb + t; i < pe; i += 256)
        atomicAdd(&cnt[gpairs[i] & 127], 1);
    __syncthreads();
    if (t < NPB) scn[t] = cnt[t];
    __syncthreads();
    for (int off = 1; off < NPB; off <<= 1) {
        int x = 0;
        if (t >= off && t < NPB) x = scn[t - off];
        __syncthreads();
        if (t < NPB) scn[t] += x;
        __syncthreads();
    }
    if (t < nn) {
        int excl = scn[t] - cnt[t];
        int o = pb + excl + lo + t;
        offs[lo + t] = o;
        cur[t] = o;
        dinv[lo + t] = rsqrtf((float)(cnt[t] + 1));
        srcs[pb + scn[t] + lo + t] = lo + t;   // self-loop at last slot
    }
    if (b == K_BUCKETS - 1 && t == 0) offs[N_NODES] = pe + N_NODES;
    __syncthreads();
    for (int i = pb + t; i < pe; i += 256) {
        uint32 u = gpairs[i];
        int pos = atomicAdd(&cur[u & 127], 1);
        srcs[pos] = (int)(u >> 7);
    }
}

// ---------- GCN1: xw1 = bf16( (x @ W1) * dinv[row] ), float2-LDS weights ------
__global__ __launch_bounds__(256) void k_gemm1(const float* __restrict__ x,
                                               const float* __restrict__ W1,
                                               const float* __restrict__ dinv,
                                               uint32* __restrict__ xw1) {
    __shared__ float wl[IN_C * HID];   // as float2[k2][f]
    __shared__ float xl[8 * IN_C];
    int t = threadIdx.x;
    for (int i = t; i < IN_C * HID; i += 256) {
        int k = i >> 5, f = i & 31;
        wl[(k >> 1) * 64 + f * 2 + (k & 1)] = W1[i];
    }
    int nb = blockIdx.x * 8;
    const float4* x4 = (const float4*)(x + (size_t)nb * IN_C);
    ((float4*)xl)[t] = x4[t];
    __syncthreads();
    int g = t >> 5, f = t & 31;
    const float2* xr = (const float2*)(xl + g * IN_C);
    const float2* wp = (const float2*)wl;
    float acc = 0.f;
#pragma unroll 16
    for (int k2 = 0; k2 < 64; k2++) {
        float2 xv = xr[k2];
        float2 wv = wp[k2 * 32 + f];
        acc += xv.x * wv.x + xv.y * wv.y;
    }
    float v = acc * dinv[nb + g];
    float vn = __shfl_xor(v, 1, 64);
    if ((f & 1) == 0) xw1[(size_t)(nb + g) * 16 + (f >> 1)] = pack_bf2(v, vn);
}

// ---------- GCN1 aggregate -> h1s (bf16) + per-node exp records ----------
// eals[n*8..]: {exp(als_h)}x4, {exp(0.2*als_h)}x4; eald likewise for ald.
__global__ __launch_bounds__(256) void k_gather1(const uint32* __restrict__ xw1,
                                                 const int* __restrict__ offs,
                                                 const int* __restrict__ srcs,
                                                 const float* __restrict__ dinv,
                                                 const float* __restrict__ b1,
                                                 const float* __restrict__ wals,
                                                 const float* __restrict__ wald,
                                                 uint32* __restrict__ h1s,
                                                 float* __restrict__ eals,
                                                 float* __restrict__ eald) {
    int t = threadIdx.x;
    int l16 = t & 15;
    int n = blockIdx.x * 16 + (t >> 4);
    int s0 = offs[n], s1 = offs[n + 1];
    const uint32* xc = xw1 + l16;
    float a0 = 0.f, a1 = 0.f, a2 = 0.f, a3 = 0.f;
    int j = s0;
    for (; j + 1 < s1; j += 2) {
        uint32 uA = xc[(size_t)srcs[j] * 16];
        uint32 uB = xc[(size_t)srcs[j + 1] * 16];
        a0 += bf_lo(uA); a1 += bf_hi(uA);
        a2 += bf_lo(uB); a3 += bf_hi(uB);
    }
    if (j < s1) {
        uint32 uA = xc[(size_t)srcs[j] * 16];
        a0 += bf_lo(uA); a1 += bf_hi(uA);
    }
    float dn = dinv[n];
    float2 b = ((const float2*)b1)[l16];
    float vx = (a0 + a2) * dn + b.x;
    float vy = (a1 + a3) * dn + b.y;
    vx = vx > 0.f ? vx : 0.f;
    vy = vy > 0.f ? vy : 0.f;
    h1s[(size_t)n * 16 + l16] = pack_bf2(vx, vy);

    float ps0, ps1, ps2, ps3, pd0, pd1, pd2, pd3;
    {
        float2 w0 = ((const float2*)wals)[0 * 16 + l16];
        float2 w1 = ((const float2*)wals)[1 * 16 + l16];
        float2 w2 = ((const float2*)wals)[2 * 16 + l16];
        float2 w3 = ((const float2*)wals)[3 * 16 + l16];
        ps0 = vx * w0.x + vy * w0.y;
        ps1 = vx * w1.x + vy * w1.y;
        ps2 = vx * w2.x + vy * w2.y;
        ps3 = vx * w3.x + vy * w3.y;
        float2 u0 = ((const float2*)wald)[0 * 16 + l16];
        float2 u1 = ((const float2*)wald)[1 * 16 + l16];
        float2 u2 = ((const float2*)wald)[2 * 16 + l16];
        float2 u3 = ((const float2*)wald)[3 * 16 + l16];
        pd0 = vx * u0.x + vy * u0.y;
        pd1 = vx * u1.x + vy * u1.y;
        pd2 = vx * u2.x + vy * u2.y;
        pd3 = vx * u3.x + vy * u3.y;
    }
#pragma unroll
    for (int m = 1; m < 16; m <<= 1) {
        ps0 += __shfl_xor(ps0, m, 16); ps1 += __shfl_xor(ps1, m, 16);
        ps2 += __shfl_xor(ps2, m, 16); ps3 += __shfl_xor(ps3, m, 16);
        pd0 += __shfl_xor(pd0, m, 16); pd1 += __shfl_xor(pd1, m, 16);
        pd2 += __shfl_xor(pd2, m, 16); pd3 += __shfl_xor(pd3, m, 16);
    }
    if (l16 == 0) {
        float4* es = (float4*)(eals + (size_t)n * 8);
        float4* ed = (float4*)(eald + (size_t)n * 8);
        es[0] = make_float4(__expf(ps0), __expf(ps1), __expf(ps2), __expf(ps3));
        es[1] = make_float4(__expf(NEG_SLOPE * ps0), __expf(NEG_SLOPE * ps1),
                            __expf(NEG_SLOPE * ps2), __expf(NEG_SLOPE * ps3));
        ed[0] = make_float4(__expf(pd0), __expf(pd1), __expf(pd2), __expf(pd3));
        ed[1] = make_float4(__expf(NEG_SLOPE * pd0), __expf(NEG_SLOPE * pd1),
                            __expf(NEG_SLOPE * pd2), __expf(NEG_SLOPE * pd3));
    }
}

// ---------- Fused GAT: shuffle-free edge aggregate + 128->32 post-GEMM --------
// 8 nodes x 32 lanes; lane (par = l32>>4) handles edges j = s0+par, +2...
// Weight per (edge, head) recomputed by all 16 lanes of the parity from
// factorized exps: w = (E1s*E1d > 1) ? E1s*E1d : E2s*E2d  (exact leaky-softmax,
// no max-shift: exp(a+b)=exp(a)exp(b); sign(t) == (exp(t)>1)). No shuffles, no
// exp in the loop; row-load address depends only on srcs[j].
__global__ __launch_bounds__(256) void k_gat_agg(const uint32* __restrict__ h1s,
                                                 const float* __restrict__ eals,
                                                 const float* __restrict__ eald,
                                                 const int* __restrict__ offs,
                                                 const int* __restrict__ srcs,
                                                 const uint32* __restrict__ wgp,
                                                 const float* __restrict__ bg,
                                                 const float* __restrict__ dinv,
                                                 uint32* __restrict__ h2s) {
    __shared__ __align__(16) uint32 wl[2048];   // packed Wg': 8 KB
    __shared__ __align__(16) uint32 gl[8][64];  // packed g: 2 KB
    int t = threadIdx.x;
    {   // stage packed weights: 2 x b128 per thread, coalesced
        const uint4* src4 = (const uint4*)wgp;
        uint4* dst4 = (uint4*)wl;
        dst4[t] = src4[t];
        dst4[256 + t] = src4[256 + t];
    }

    int l32 = t & 31;
    int g8 = t >> 5;             // node slot in block
    int n = blockIdx.x * 8 + g8;
    int l16 = l32 & 15;
    int par = l32 >> 4;          // edge parity this lane gathers
    int s0 = offs[n], s1 = offs[n + 1];
    const float4* edp = (const float4*)(eald + (size_t)n * 8);
    float4 d1 = edp[0];          // exp(ald_h)
    float4 d2 = edp[1];          // exp(0.2*ald_h)

    float g00 = 0.f, g01 = 0.f, g10 = 0.f, g11 = 0.f;
    float g20 = 0.f, g21 = 0.f, g30 = 0.f, g31 = 0.f;
    float ss0 = 0.f, ss1 = 0.f, ss2 = 0.f, ss3 = 0.f;

#define GAT_EDGE(J)                                                            \
    {                                                                          \
        int sq = srcs[J];                                                      \
        const float4* esp = (const float4*)(eals + (size_t)sq * 8);            \
        float4 e1 = esp[0];                                                    \
        float4 e2 = esp[1];                                                    \
        uint32 u = h1s[(size_t)sq * 16 + l16];                                 \
        float flo = bf_lo(u), fhi = bf_hi(u);                                  \
        float p, q, w;                                                         \
        p = e1.x * d1.x; q = e2.x * d2.x; w = p > 1.f ? p : q;                 \
        ss0 += w; g00 += w * flo; g01 += w * fhi;                              \
        p = e1.y * d1.y; q = e2.y * d2.y; w = p > 1.f ? p : q;                 \
        ss1 += w; g10 += w * flo; g11 += w * fhi;                              \
        p = e1.z * d1.z; q = e2.z * d2.z; w = p > 1.f ? p : q;                 \
        ss2 += w; g20 += w * flo; g21 += w * fhi;                              \
        p = e1.w * d1.w; q = e2.w * d2.w; w = p > 1.f ? p : q;                 \
        ss3 += w; g30 += w * flo; g31 += w * fhi;                              \
    }

    int j = s0 + par;
    for (; j + 2 < s1; j += 4) {   // unroll 2 for MLP
        GAT_EDGE(j);
        GAT_EDGE(j + 2);
    }
    if (j < s1) GAT_EDGE(j);
#undef GAT_EDGE

    // combine edge-parity halves (lanes l32 ^ 16)
    ss0 += __shfl_xor(ss0, 16, 64); ss1 += __shfl_xor(ss1, 16, 64);
    ss2 += __shfl_xor(ss2, 16, 64); ss3 += __shfl_xor(ss3, 16, 64);
    g00 += __shfl_xor(g00, 16, 64); g01 += __shfl_xor(g01, 16, 64);
    g10 += __shfl_xor(g10, 16, 64); g11 += __shfl_xor(g11, 16, 64);
    g20 += __shfl_xor(g20, 16, 64); g21 += __shfl_xor(g21, 16, 64);
    g30 += __shfl_xor(g30, 16, 64); g31 += __shfl_xor(g31, 16, 64);
    float i0 = 0.25f / ss0, i1 = 0.25f / ss1, i2 = 0.25f / ss2, i3 = 0.25f / ss3;
    if (l32 < 16) {
        gl[g8][0 * 16 + l16] = pack_bf2(g00 * i0, g01 * i0);
        gl[g8][1 * 16 + l16] = pack_bf2(g10 * i1, g11 * i1);
        gl[g8][2 * 16 + l16] = pack_bf2(g20 * i2, g21 * i2);
        gl[g8][3 * 16 + l16] = pack_bf2(g30 * i3, g31 * i3);
    }
    __syncthreads();
    // epilogue: d = l32; acc = sum_c g[c] * Wg'[c][d], 4 channels per iter
    const uint2* gv = (const uint2*)gl[g8];
    const uint2* wp = (const uint2*)wl;
    int d = l32;
    float acc = 0.f;
#pragma unroll 8
    for (int j4 = 0; j4 < 32; j4++) {
        uint2 gg = gv[j4];            // channels 4j4..4j4+3 (broadcast)
        uint2 ww = wp[j4 * 32 + d];
        acc += bf_lo(gg.x) * bf_lo(ww.x) + bf_hi(gg.x) * bf_hi(ww.x)
             + bf_lo(gg.y) * bf_lo(ww.y) + bf_hi(gg.y) * bf_hi(ww.y);
    }
    float v = acc + bg[d];
    v = v > 0.f ? v : 0.f;
    v *= dinv[n];
    float vn = __shfl_xor(v, 1, 64);
    if ((d & 1) == 0) h2s[(size_t)n * 16 + (d >> 1)] = pack_bf2(v, vn);
}

// ---------- Fused GCN2: edge aggregate in h2-space + 32->64 output GEMM -------
__global__ __launch_bounds__(256) void k_gather2(const uint32* __restrict__ h2s,
                                                 const int* __restrict__ offs,
                                                 const int* __restrict__ srcs,
                                                 const uint32* __restrict__ w2p,
                                                 const float* __restrict__ dinv,
                                                 const float* __restrict__ b2,
                                                 float* __restrict__ out) {
    __shared__ __align__(16) uint32 wl[1024];    // packed W2: 4 KB
    __shared__ __align__(16) uint32 gbf[16][16]; // packed g2: 1 KB
    int t = threadIdx.x;
    ((uint4*)wl)[t] = ((const uint4*)w2p)[t];    // 1 b128 per thread

    int l16 = t & 15;
    int g16 = t >> 4;
    int n = blockIdx.x * 16 + g16;
    int s0 = offs[n], s1 = offs[n + 1];
    const uint32* xc = h2s + l16;
    float a0 = 0.f, a1 = 0.f, a2 = 0.f, a3 = 0.f;
    int j = s0;
    for (; j + 1 < s1; j += 2) {
        uint32 uA = xc[(size_t)srcs[j] * 16];
        uint32 uB = xc[(size_t)srcs[j + 1] * 16];
        a0 += bf_lo(uA); a1 += bf_hi(uA);
        a2 += bf_lo(uB); a3 += bf_hi(uB);
    }
    if (j < s1) {
        uint32 uA = xc[(size_t)srcs[j] * 16];
        a0 += bf_lo(uA); a1 += bf_hi(uA);
    }
    gbf[g16][l16] = pack_bf2(a0 + a2, a1 + a3);
    __syncthreads();
    const uint2* gv = (const uint2*)gbf[g16];
    const uint2* wp = (const uint2*)wl;
    float dn = dinv[n];
    float acc0 = 0.f, acc1 = 0.f, acc2 = 0.f, acc3 = 0.f;
#pragma unroll
    for (int k4 = 0; k4 < 8; k4++) {
        uint2 gg = gv[k4];            // channels 4k4..4k4+3 (broadcast)
        float gx = bf_lo(gg.x), gy = bf_hi(gg.x);
        float gz = bf_lo(gg.y), gw = bf_hi(gg.y);
        uint2 w0 = wp[k4 * 64 + l16];
        uint2 w1 = wp[k4 * 64 + l16 + 16];
        uint2 w2 = wp[k4 * 64 + l16 + 32];
        uint2 w3 = wp[k4 * 64 + l16 + 48];
        acc0 += gx * bf_lo(w0.x) + gy * bf_hi(w0.x) + gz * bf_lo(w0.y) + gw * bf_hi(w0.y);
        acc1 += gx * bf_lo(w1.x) + gy * bf_hi(w1.x) + gz * bf_lo(w1.y) + gw * bf_hi(w1.y);
        acc2 += gx * bf_lo(w2.x) + gy * bf_hi(w2.x) + gz * bf_lo(w2.y) + gw * bf_hi(w2.y);
        acc3 += gx * bf_lo(w3.x) + gy * bf_hi(w3.x) + gz * bf_lo(w3.y) + gw * bf_hi(w3.y);
    }
    float* op = out + (size_t)n * OUT_C;
    op[l16]      = acc0 * dn + b2[l16];
    op[l16 + 16] = acc1 * dn + b2[l16 + 16];
    op[l16 + 32] = acc2 * dn + b2[l16 + 32];
    op[l16 + 48] = acc3 * dn + b2[l16 + 48];
}

extern "C" void kernel_launch(void* const* d_in, const int* in_sizes, int n_in,
                              void* d_out, int out_size, void* d_ws, size_t ws_size,
                              hipStream_t stream) {
    const float* x   = (const float*)d_in[0];
    const int*   ei  = (const int*)d_in[1];   // int64 in reference -> int32 from harness
    const float* W1  = (const float*)d_in[2];
    const float* b1  = (const float*)d_in[3];
    const float* Wg  = (const float*)d_in[4];
    const float* ags = (const float*)d_in[5];
    const float* agd = (const float*)d_in[6];
    const float* bg  = (const float*)d_in[7];
    const float* W2  = (const float*)d_in[8];
    const float* b2  = (const float*)d_in[9];
    float* out = (float*)d_out;

    char* p = (char*)d_ws;
    auto alloc = [&](size_t bytes) -> void* {
        void* r = (void*)p;
        p += (bytes + 255) & ~(size_t)255;
        return r;
    };
    float*  dinv    = (float*)alloc((size_t)N_NODES * 4);
    int*    offs    = (int*)  alloc((size_t)(N_NODES + 1) * 4);
    int*    gcnt    = (int*)  alloc((size_t)(K_BUCKETS + 1) * 4);
    int*    gbase   = (int*)  alloc((size_t)(K_BUCKETS + 1) * 4);
    int*    gcursor = (int*)  alloc((size_t)(K_BUCKETS + 1) * 4);
    int*    srcs    = (int*)  alloc((size_t)EP * 4);
    uint32* gpairs  = (uint32*)alloc((size_t)N_EDGES * 4);
    uint32* xw1     = (uint32*)alloc((size_t)N_NODES * 16 * 4);
    uint32* h1s     = (uint32*)alloc((size_t)N_NODES * 16 * 4);
    float*  eals    = (float*)alloc((size_t)N_NODES * 8 * 4);
    float*  eald    = (float*)alloc((size_t)N_NODES * 8 * 4);
    float*  wals    = (float*)alloc(128 * 4);
    float*  wald    = (float*)alloc(128 * 4);
    uint32* wgp     = (uint32*)alloc(2048 * 4);
    uint32* w2p     = (uint32*)alloc(1024 * 4);
    uint32* h2s     = (uint32*)alloc((size_t)N_NODES * 16 * 4);

    // init + CSR build (two-level bucket sort)
    k_init2<<<1, 512, 0, stream>>>(gcnt, Wg, ags, agd, wals, wald, W2, wgp, w2p);
    k_bcount<<<(N_EDGES + 4095) / 4096, 256, 0, stream>>>(ei, gcnt);
    k_bscan<<<1, 512, 0, stream>>>(gcnt, gbase, gcursor);
    k_bucket<<<(N_EDGES + 2047) / 2048, 256, 0, stream>>>(ei, gcursor, gpairs);
    k_node<<<K_BUCKETS, 256, 0, stream>>>(gpairs, gbase, offs, dinv, srcs);

    // GCN1
    k_gemm1<<<N_NODES / 8, 256, 0, stream>>>(x, W1, dinv, xw1);
    k_gather1<<<N_NODES / 16, 256, 0, stream>>>(xw1, offs, srcs, dinv, b1,
                                                wals, wald, h1s, eals, eald);

    // GAT: shuffle-free edge aggregate + fused post-GEMM
    k_gat_agg<<<N_NODES / 8, 256, 0, stream>>>(h1s, eals, eald, offs, srcs,
                                               wgp, bg, dinv, h2s);

    // GCN2: edge aggregate + fused output GEMM
    k_gather2<<<N_NODES / 16, 256, 0, stream>>>(h2s, offs, srcs, w2p, dinv, b2, out);
}

// Round 12
// 233.297 us; speedup vs baseline: 1.0153x; 1.0123x over previous
//
#include <hip/hip_runtime.h>
#include <hip/hip_bf16.h>

// Problem constants (from reference)
#define N_NODES 50000
#define N_EDGES 800000
#define EP (N_EDGES + N_NODES)   // edges incl. self loops = 850000
#define IN_C 128
#define HID 32
#define OUT_C 64
#define HEADS 4
#define NEG_SLOPE 0.2f

#define NPB 128                          // nodes per bucket (power of 2)
#define K_BUCKETS ((N_NODES + NPB - 1) / NPB)   // 391

typedef unsigned int uint32;

__device__ __forceinline__ float bf_lo(uint32 u) { return __uint_as_float(u << 16); }
__device__ __forceinline__ float bf_hi(uint32 u) { return __uint_as_float(u & 0xffff0000u); }
// round-to-nearest-even f32 -> bf16 (no NaN inputs here)
__device__ __forceinline__ uint32 f2bf(float f) {
    uint32 u = __float_as_uint(f);
    return (u + 0x7fffu + ((u >> 16) & 1u)) >> 16;
}
__device__ __forceinline__ uint32 pack_bf2(float a, float b) {
    return f2bf(a) | (f2bf(b) << 16);
}

// ---------- init: zero bucket counts + attention vectors + packed weights -----
__global__ __launch_bounds__(512) void k_init2(int* __restrict__ gcnt,
                                               const float* __restrict__ Wg,
                                               const float* __restrict__ ags,
                                               const float* __restrict__ agd,
                                               float* __restrict__ wals,
                                               float* __restrict__ wald,
                                               const float* __restrict__ W2,
                                               uint32* __restrict__ wgp,
                                               uint32* __restrict__ w2p) {
    int t = threadIdx.x;
    if (t < K_BUCKETS + 1) gcnt[t] = 0;
    if (t < 256) {
        int c = t & 127;
        int h = c >> 5, k = c & 31;
        const float* a = (t < 128) ? ags : agd;
        float acc = 0.f;
#pragma unroll
        for (int d = 0; d < 32; d++) acc += Wg[k * 128 + h * 32 + d] * a[h * 32 + d];
        if (t < 128) wals[c] = acc; else wald[c] = acc;
    }
    for (int i = t; i < 2048; i += 512) {
        int j4 = i >> 6, d = (i >> 1) & 31, pp = i & 1;
        int c0 = 4 * j4 + 2 * pp, c1 = c0 + 1;
        float a = Wg[(c0 & 31) * 128 + (c0 >> 5) * 32 + d];
        float b = Wg[(c1 & 31) * 128 + (c1 >> 5) * 32 + d];
        wgp[i] = pack_bf2(a, b);
    }
    for (int i = t; i < 1024; i += 512) {
        int k4 = i >> 7, d = (i >> 1) & 63, pp = i & 1;
        int r0 = 4 * k4 + 2 * pp, r1 = r0 + 1;
        w2p[i] = pack_bf2(W2[r0 * 64 + d], W2[r1 * 64 + d]);
    }
}

// ---------- CSR build via two-level bucket sort ----------

__global__ __launch_bounds__(256) void k_bcount(const int* __restrict__ ei,
                                                int* __restrict__ gcnt) {
    __shared__ int h[K_BUCKETS];
    int t = threadIdx.x;
    for (int i = t; i < K_BUCKETS; i += 256) h[i] = 0;
    __syncthreads();
    int base = blockIdx.x * 4096;
    int dd[16];
#pragma unroll
    for (int k = 0; k < 16; k++) {
        int e = base + k * 256 + t;
        dd[k] = (e < N_EDGES) ? ei[N_EDGES + e] : -1;
    }
#pragma unroll
    for (int k = 0; k < 16; k++)
        if (dd[k] >= 0) atomicAdd(&h[dd[k] >> 7], 1);
    __syncthreads();
    for (int i = t; i < K_BUCKETS; i += 256)
        if (h[i]) atomicAdd(&gcnt[i], h[i]);
}

__global__ __launch_bounds__(512) void k_bscan(const int* __restrict__ gcnt,
                                               int* __restrict__ gbase,
                                               int* __restrict__ gcursor) {
    __shared__ int sd[512];
    int t = threadIdx.x;
    int v = (t < K_BUCKETS) ? gcnt[t] : 0;
    sd[t] = v;
    __syncthreads();
    for (int off = 1; off < 512; off <<= 1) {
        int x = (t >= off) ? sd[t - off] : 0;
        __syncthreads();
        sd[t] += x;
        __syncthreads();
    }
    if (t < K_BUCKETS) {
        int excl = sd[t] - v;
        gbase[t] = excl;
        gcursor[t] = excl;
    }
    if (t == 0) gbase[K_BUCKETS] = sd[K_BUCKETS - 1];
}

__global__ __launch_bounds__(256) void k_bucket(const int* __restrict__ ei,
                                                int* __restrict__ gcursor,
                                                uint32* __restrict__ gpairs) {
    __shared__ int cnt[K_BUCKETS];
    __shared__ int bas[K_BUCKETS];
    int t = threadIdx.x;
    for (int i = t; i < K_BUCKETS; i += 256) cnt[i] = 0;
    __syncthreads();
    int base = blockIdx.x * 2048;
    int ss[8], dd[8], ml[8];
#pragma unroll
    for (int k = 0; k < 8; k++) {
        int e = base + k * 256 + t;
        ss[k] = (e < N_EDGES) ? ei[e] : -1;
        dd[k] = (e < N_EDGES) ? ei[N_EDGES + e] : 0;
    }
#pragma unroll
    for (int k = 0; k < 8; k++)
        if (ss[k] >= 0) ml[k] = atomicAdd(&cnt[dd[k] >> 7], 1);
    __syncthreads();
    for (int i = t; i < K_BUCKETS; i += 256)
        bas[i] = cnt[i] ? atomicAdd(&gcursor[i], cnt[i]) : 0;
    __syncthreads();
#pragma unroll
    for (int k = 0; k < 8; k++)
        if (ss[k] >= 0)
            gpairs[bas[dd[k] >> 7] + ml[k]] = ((uint32)ss[k] << 7) | (uint32)(dd[k] & 127);
}

__global__ __launch_bounds__(256) void k_node(const uint32* __restrict__ gpairs,
                                              const int* __restrict__ gbase,
                                              int* __restrict__ offs,
                                              float* __restrict__ dinv,
                                              int* __restrict__ srcs) {
    __shared__ int cnt[NPB];
    __shared__ int scn[NPB];
    __shared__ int cur[NPB];
    int t = threadIdx.x;
    int b = blockIdx.x;
    int lo = b << 7;
    int nn = N_NODES - lo; if (nn > NPB) nn = NPB;
    int pb = gbase[b], pe = gbase[b + 1];
    if (t < NPB) cnt[t] = 0;
    __syncthreads();
    for (int i = pb + t; i < pe; i += 256)
        atomicAdd(&cnt[gpairs[i] & 127], 1);
    __syncthreads();
    if (t < NPB) scn[t] = cnt[t];
    __syncthreads();
    for (int off = 1; off < NPB; off <<= 1) {
        int x = 0;
        if (t >= off && t < NPB) x = scn[t - off];
        __syncthreads();
        if (t < NPB) scn[t] += x;
        __syncthreads();
    }
    if (t < nn) {
        int excl = scn[t] - cnt[t];
        int o = pb + excl + lo + t;
        offs[lo + t] = o;
        cur[t] = o;
        dinv[lo + t] = rsqrtf((float)(cnt[t] + 1));
        srcs[pb + scn[t] + lo + t] = lo + t;   // self-loop at last slot
    }
    if (b == K_BUCKETS - 1 && t == 0) offs[N_NODES] = pe + N_NODES;
    __syncthreads();
    for (int i = pb + t; i < pe; i += 256) {
        uint32 u = gpairs[i];
        int pos = atomicAdd(&cur[u & 127], 1);
        srcs[pos] = (int)(u >> 7);
    }
}

// ---------- GCN1: xw1 = bf16( (x @ W1) * dinv[row] ), float2-LDS weights ------
__global__ __launch_bounds__(256) void k_gemm1(const float* __restrict__ x,
                                               const float* __restrict__ W1,
                                               const float* __restrict__ dinv,
                                               uint32* __restrict__ xw1) {
    __shared__ float wl[IN_C * HID];   // as float2[k2][f]
    __shared__ float xl[8 * IN_C];
    int t = threadIdx.x;
    for (int i = t; i < IN_C * HID; i += 256) {
        int k = i >> 5, f = i & 31;
        wl[(k >> 1) * 64 + f * 2 + (k & 1)] = W1[i];
    }
    int nb = blockIdx.x * 8;
    const float4* x4 = (const float4*)(x + (size_t)nb * IN_C);
    ((float4*)xl)[t] = x4[t];
    __syncthreads();
    int g = t >> 5, f = t & 31;
    const float2* xr = (const float2*)(xl + g * IN_C);
    const float2* wp = (const float2*)wl;
    float acc = 0.f;
#pragma unroll 16
    for (int k2 = 0; k2 < 64; k2++) {
        float2 xv = xr[k2];
        float2 wv = wp[k2 * 32 + f];
        acc += xv.x * wv.x + xv.y * wv.y;
    }
    float v = acc * dinv[nb + g];
    float vn = __shfl_xor(v, 1, 64);
    if ((f & 1) == 0) xw1[(size_t)(nb + g) * 16 + (f >> 1)] = pack_bf2(v, vn);
}

// ---------- GCN1 aggregate -> per-node 128B record ----------
// rec[n] (128B aligned): [0:16) e1s=exp(als_h), [16:32) e2s=exp(.2 als_h),
// [32:48) e1d, [48:64) e2d, [64:128) h1 as 16 packed-bf16 words.
__global__ __launch_bounds__(256) void k_gather1(const uint32* __restrict__ xw1,
                                                 const int* __restrict__ offs,
                                                 const int* __restrict__ srcs,
                                                 const float* __restrict__ dinv,
                                                 const float* __restrict__ b1,
                                                 const float* __restrict__ wals,
                                                 const float* __restrict__ wald,
                                                 char* __restrict__ rec) {
    int t = threadIdx.x;
    int l16 = t & 15;
    int n = blockIdx.x * 16 + (t >> 4);
    int s0 = offs[n], s1 = offs[n + 1];
    const char* xb = (const char*)xw1 + l16 * 4;
    float a0 = 0.f, a1 = 0.f, a2 = 0.f, a3 = 0.f;
    int j = s0;
    for (; j + 1 < s1; j += 2) {
        uint32 uA = *(const uint32*)(xb + ((uint32)srcs[j] << 6));
        uint32 uB = *(const uint32*)(xb + ((uint32)srcs[j + 1] << 6));
        a0 += bf_lo(uA); a1 += bf_hi(uA);
        a2 += bf_lo(uB); a3 += bf_hi(uB);
    }
    if (j < s1) {
        uint32 uA = *(const uint32*)(xb + ((uint32)srcs[j] << 6));
        a0 += bf_lo(uA); a1 += bf_hi(uA);
    }
    float dn = dinv[n];
    float2 b = ((const float2*)b1)[l16];
    float vx = (a0 + a2) * dn + b.x;
    float vy = (a1 + a3) * dn + b.y;
    vx = vx > 0.f ? vx : 0.f;
    vy = vy > 0.f ? vy : 0.f;
    char* rn = rec + (size_t)n * 128;
    *(uint32*)(rn + 64 + l16 * 4) = pack_bf2(vx, vy);

    float ps0, ps1, ps2, ps3, pd0, pd1, pd2, pd3;
    {
        float2 w0 = ((const float2*)wals)[0 * 16 + l16];
        float2 w1 = ((const float2*)wals)[1 * 16 + l16];
        float2 w2 = ((const float2*)wals)[2 * 16 + l16];
        float2 w3 = ((const float2*)wals)[3 * 16 + l16];
        ps0 = vx * w0.x + vy * w0.y;
        ps1 = vx * w1.x + vy * w1.y;
        ps2 = vx * w2.x + vy * w2.y;
        ps3 = vx * w3.x + vy * w3.y;
        float2 u0 = ((const float2*)wald)[0 * 16 + l16];
        float2 u1 = ((const float2*)wald)[1 * 16 + l16];
        float2 u2 = ((const float2*)wald)[2 * 16 + l16];
        float2 u3 = ((const float2*)wald)[3 * 16 + l16];
        pd0 = vx * u0.x + vy * u0.y;
        pd1 = vx * u1.x + vy * u1.y;
        pd2 = vx * u2.x + vy * u2.y;
        pd3 = vx * u3.x + vy * u3.y;
    }
#pragma unroll
    for (int m = 1; m < 16; m <<= 1) {
        ps0 += __shfl_xor(ps0, m, 16); ps1 += __shfl_xor(ps1, m, 16);
        ps2 += __shfl_xor(ps2, m, 16); ps3 += __shfl_xor(ps3, m, 16);
        pd0 += __shfl_xor(pd0, m, 16); pd1 += __shfl_xor(pd1, m, 16);
        pd2 += __shfl_xor(pd2, m, 16); pd3 += __shfl_xor(pd3, m, 16);
    }
    if (l16 == 0) {
        float4* r4 = (float4*)rn;
        r4[0] = make_float4(__expf(ps0), __expf(ps1), __expf(ps2), __expf(ps3));
        r4[1] = make_float4(__expf(NEG_SLOPE * ps0), __expf(NEG_SLOPE * ps1),
                            __expf(NEG_SLOPE * ps2), __expf(NEG_SLOPE * ps3));
        r4[2] = make_float4(__expf(pd0), __expf(pd1), __expf(pd2), __expf(pd3));
        r4[3] = make_float4(__expf(NEG_SLOPE * pd0), __expf(NEG_SLOPE * pd1),
                            __expf(NEG_SLOPE * pd2), __expf(NEG_SLOPE * pd3));
    }
}

// ---------- Fused GAT: record-based edge aggregate + 128->32 post-GEMM --------
// 8 nodes x 32 lanes; parity split. Per edge: ONE address (sq<<7) + 3 loads at
// fixed offsets into the 128B record; weight from factorized exps (no exp, no
// shuffles in loop). w = (E1s*E1d > 1) ? E1s*E1d : E2s*E2d.
__global__ __launch_bounds__(256) void k_gat_agg(const char* __restrict__ rec,
                                                 const int* __restrict__ offs,
                                                 const int* __restrict__ srcs,
                                                 const uint32* __restrict__ wgp,
                                                 const float* __restrict__ bg,
                                                 const float* __restrict__ dinv,
                                                 uint32* __restrict__ h2s) {
    __shared__ __align__(16) uint32 wl[2048];   // packed Wg': 8 KB
    __shared__ __align__(16) uint32 gl[8][64];  // packed g: 2 KB
    int t = threadIdx.x;
    {   // stage packed weights: 2 x b128 per thread, coalesced
        const uint4* src4 = (const uint4*)wgp;
        uint4* dst4 = (uint4*)wl;
        dst4[t] = src4[t];
        dst4[256 + t] = src4[256 + t];
    }

    int l32 = t & 31;
    int g8 = t >> 5;             // node slot in block
    int n = blockIdx.x * 8 + g8;
    int l16 = l32 & 15;
    int par = l32 >> 4;          // edge parity this lane gathers
    int s0 = offs[n], s1 = offs[n + 1];
    const float4* dn4 = (const float4*)(rec + (size_t)n * 128);
    float4 d1 = dn4[2];          // e1d
    float4 d2 = dn4[3];          // e2d
    uint32 hoff = 64 + l16 * 4;  // lane's h1 word offset within record

    float g00 = 0.f, g01 = 0.f, g10 = 0.f, g11 = 0.f;
    float g20 = 0.f, g21 = 0.f, g30 = 0.f, g31 = 0.f;
    float ss0 = 0.f, ss1 = 0.f, ss2 = 0.f, ss3 = 0.f;

#define GAT_EDGE(J)                                                            \
    {                                                                          \
        uint32 off = (uint32)srcs[J] << 7;                                     \
        float4 e1 = *(const float4*)(rec + off);                               \
        float4 e2 = *(const float4*)(rec + off + 16);                          \
        uint32 u = *(const uint32*)(rec + off + hoff);                         \
        float flo = bf_lo(u), fhi = bf_hi(u);                                  \
        float p, q, w;                                                         \
        p = e1.x * d1.x; q = e2.x * d2.x; w = p > 1.f ? p : q;                 \
        ss0 += w; g00 += w * flo; g01 += w * fhi;                              \
        p = e1.y * d1.y; q = e2.y * d2.y; w = p > 1.f ? p : q;                 \
        ss1 += w; g10 += w * flo; g11 += w * fhi;                              \
        p = e1.z * d1.z; q = e2.z * d2.z; w = p > 1.f ? p : q;                 \
        ss2 += w; g20 += w * flo; g21 += w * fhi;                              \
        p = e1.w * d1.w; q = e2.w * d2.w; w = p > 1.f ? p : q;                 \
        ss3 += w; g30 += w * flo; g31 += w * fhi;                              \
    }

    int j = s0 + par;
    for (; j + 2 < s1; j += 4) {   // unroll 2 for MLP
        GAT_EDGE(j);
        GAT_EDGE(j + 2);
    }
    if (j < s1) GAT_EDGE(j);
#undef GAT_EDGE

    // combine edge-parity halves (lanes l32 ^ 16)
    ss0 += __shfl_xor(ss0, 16, 64); ss1 += __shfl_xor(ss1, 16, 64);
    ss2 += __shfl_xor(ss2, 16, 64); ss3 += __shfl_xor(ss3, 16, 64);
    g00 += __shfl_xor(g00, 16, 64); g01 += __shfl_xor(g01, 16, 64);
    g10 += __shfl_xor(g10, 16, 64); g11 += __shfl_xor(g11, 16, 64);
    g20 += __shfl_xor(g20, 16, 64); g21 += __shfl_xor(g21, 16, 64);
    g30 += __shfl_xor(g30, 16, 64); g31 += __shfl_xor(g31, 16, 64);
    float i0 = 0.25f / ss0, i1 = 0.25f / ss1, i2 = 0.25f / ss2, i3 = 0.25f / ss3;
    if (l32 < 16) {
        gl[g8][0 * 16 + l16] = pack_bf2(g00 * i0, g01 * i0);
        gl[g8][1 * 16 + l16] = pack_bf2(g10 * i1, g11 * i1);
        gl[g8][2 * 16 + l16] = pack_bf2(g20 * i2, g21 * i2);
        gl[g8][3 * 16 + l16] = pack_bf2(g30 * i3, g31 * i3);
    }
    __syncthreads();
    // epilogue: d = l32; acc = sum_c g[c] * Wg'[c][d], 4 channels per iter
    const uint2* gv = (const uint2*)gl[g8];
    const uint2* wp = (const uint2*)wl;
    int d = l32;
    float acc = 0.f;
#pragma unroll 8
    for (int j4 = 0; j4 < 32; j4++) {
        uint2 gg = gv[j4];            // channels 4j4..4j4+3 (broadcast)
        uint2 ww = wp[j4 * 32 + d];
        acc += bf_lo(gg.x) * bf_lo(ww.x) + bf_hi(gg.x) * bf_hi(ww.x)
             + bf_lo(gg.y) * bf_lo(ww.y) + bf_hi(gg.y) * bf_hi(ww.y);
    }
    float v = acc + bg[d];
    v = v > 0.f ? v : 0.f;
    v *= dinv[n];
    float vn = __shfl_xor(v, 1, 64);
    if ((d & 1) == 0) h2s[(size_t)n * 16 + (d >> 1)] = pack_bf2(v, vn);
}

// ---------- Fused GCN2: edge aggregate in h2-space + 32->64 output GEMM -------
__global__ __launch_bounds__(256) void k_gather2(const uint32* __restrict__ h2s,
                                                 const int* __restrict__ offs,
                                                 const int* __restrict__ srcs,
                                                 const uint32* __restrict__ w2p,
                                                 const float* __restrict__ dinv,
                                                 const float* __restrict__ b2,
                                                 float* __restrict__ out) {
    __shared__ __align__(16) uint32 wl[1024];    // packed W2: 4 KB
    __shared__ __align__(16) uint32 gbf[16][16]; // packed g2: 1 KB
    int t = threadIdx.x;
    ((uint4*)wl)[t] = ((const uint4*)w2p)[t];    // 1 b128 per thread

    int l16 = t & 15;
    int g16 = t >> 4;
    int n = blockIdx.x * 16 + g16;
    int s0 = offs[n], s1 = offs[n + 1];
    const char* xb = (const char*)h2s + l16 * 4;
    float a0 = 0.f, a1 = 0.f, a2 = 0.f, a3 = 0.f;
    int j = s0;
    for (; j + 1 < s1; j += 2) {
        uint32 uA = *(const uint32*)(xb + ((uint32)srcs[j] << 6));
        uint32 uB = *(const uint32*)(xb + ((uint32)srcs[j + 1] << 6));
        a0 += bf_lo(uA); a1 += bf_hi(uA);
        a2 += bf_lo(uB); a3 += bf_hi(uB);
    }
    if (j < s1) {
        uint32 uA = *(const uint32*)(xb + ((uint32)srcs[j] << 6));
        a0 += bf_lo(uA); a1 += bf_hi(uA);
    }
    gbf[g16][l16] = pack_bf2(a0 + a2, a1 + a3);
    __syncthreads();
    const uint2* gv = (const uint2*)gbf[g16];
    const uint2* wp = (const uint2*)wl;
    float dn = dinv[n];
    float acc0 = 0.f, acc1 = 0.f, acc2 = 0.f, acc3 = 0.f;
#pragma unroll
    for (int k4 = 0; k4 < 8; k4++) {
        uint2 gg = gv[k4];            // channels 4k4..4k4+3 (broadcast)
        float gx = bf_lo(gg.x), gy = bf_hi(gg.x);
        float gz = bf_lo(gg.y), gw = bf_hi(gg.y);
        uint2 w0 = wp[k4 * 64 + l16];
        uint2 w1 = wp[k4 * 64 + l16 + 16];
        uint2 w2 = wp[k4 * 64 + l16 + 32];
        uint2 w3 = wp[k4 * 64 + l16 + 48];
        acc0 += gx * bf_lo(w0.x) + gy * bf_hi(w0.x) + gz * bf_lo(w0.y) + gw * bf_hi(w0.y);
        acc1 += gx * bf_lo(w1.x) + gy * bf_hi(w1.x) + gz * bf_lo(w1.y) + gw * bf_hi(w1.y);
        acc2 += gx * bf_lo(w2.x) + gy * bf_hi(w2.x) + gz * bf_lo(w2.y) + gw * bf_hi(w2.y);
        acc3 += gx * bf_lo(w3.x) + gy * bf_hi(w3.x) + gz * bf_lo(w3.y) + gw * bf_hi(w3.y);
    }
    float* op = out + (size_t)n * OUT_C;
    op[l16]      = acc0 * dn + b2[l16];
    op[l16 + 16] = acc1 * dn + b2[l16 + 16];
    op[l16 + 32] = acc2 * dn + b2[l16 + 32];
    op[l16 + 48] = acc3 * dn + b2[l16 + 48];
}

extern "C" void kernel_launch(void* const* d_in, const int* in_sizes, int n_in,
                              void* d_out, int out_size, void* d_ws, size_t ws_size,
                              hipStream_t stream) {
    const float* x   = (const float*)d_in[0];
    const int*   ei  = (const int*)d_in[1];   // int64 in reference -> int32 from harness
    const float* W1  = (const float*)d_in[2];
    const float* b1  = (const float*)d_in[3];
    const float* Wg  = (const float*)d_in[4];
    const float* ags = (const float*)d_in[5];
    const float* agd = (const float*)d_in[6];
    const float* bg  = (const float*)d_in[7];
    const float* W2  = (const float*)d_in[8];
    const float* b2  = (const float*)d_in[9];
    float* out = (float*)d_out;

    char* p = (char*)d_ws;
    auto alloc = [&](size_t bytes) -> void* {
        void* r = (void*)p;
        p += (bytes + 255) & ~(size_t)255;
        return r;
    };
    float*  dinv    = (float*)alloc((size_t)N_NODES * 4);
    int*    offs    = (int*)  alloc((size_t)(N_NODES + 1) * 4);
    int*    gcnt    = (int*)  alloc((size_t)(K_BUCKETS + 1) * 4);
    int*    gbase   = (int*)  alloc((size_t)(K_BUCKETS + 1) * 4);
    int*    gcursor = (int*)  alloc((size_t)(K_BUCKETS + 1) * 4);
    int*    srcs    = (int*)  alloc((size_t)EP * 4);
    uint32* gpairs  = (uint32*)alloc((size_t)N_EDGES * 4);
    uint32* xw1     = (uint32*)alloc((size_t)N_NODES * 16 * 4);
    char*   rec     = (char*) alloc((size_t)N_NODES * 128);
    float*  wals    = (float*)alloc(128 * 4);
    float*  wald    = (float*)alloc(128 * 4);
    uint32* wgp     = (uint32*)alloc(2048 * 4);
    uint32* w2p     = (uint32*)alloc(1024 * 4);
    uint32* h2s     = (uint32*)alloc((size_t)N_NODES * 16 * 4);

    // init + CSR build (two-level bucket sort)
    k_init2<<<1, 512, 0, stream>>>(gcnt, Wg, ags, agd, wals, wald, W2, wgp, w2p);
    k_bcount<<<(N_EDGES + 4095) / 4096, 256, 0, stream>>>(ei, gcnt);
    k_bscan<<<1, 512, 0, stream>>>(gcnt, gbase, gcursor);
    k_bucket<<<(N_EDGES + 2047) / 2048, 256, 0, stream>>>(ei, gcursor, gpairs);
    k_node<<<K_BUCKETS, 256, 0, stream>>>(gpairs, gbase, offs, dinv, srcs);

    // GCN1
    k_gemm1<<<N_NODES / 8, 256, 0, stream>>>(x, W1, dinv, xw1);
    k_gather1<<<N_NODES / 16, 256, 0, stream>>>(xw1, offs, srcs, dinv, b1,
                                                wals, wald, rec);

    // GAT: record-based edge aggregate + fused post-GEMM
    k_gat_agg<<<N_NODES / 8, 256, 0, stream>>>(rec, offs, srcs, wgp, bg, dinv, h2s);

    // GCN2: edge aggregate + fused output GEMM
    k_gather2<<<N_NODES / 16, 256, 0, stream>>>(h2s, offs, srcs, w2p, dinv, b2, out);
}

// Round 13
// 218.244 us; speedup vs baseline: 1.0853x; 1.0690x over previous
//
#include <hip/hip_runtime.h>
#include <hip/hip_bf16.h>

// Problem constants (from reference)
#define N_NODES 50000
#define N_EDGES 800000
#define EP (N_EDGES + N_NODES)   // edges incl. self loops = 850000
#define IN_C 128
#define HID 32
#define OUT_C 64
#define HEADS 4
#define NEG_SLOPE 0.2f

#define NPB 128                          // nodes per bucket (power of 2)
#define K_BUCKETS ((N_NODES + NPB - 1) / NPB)   // 391

typedef unsigned int uint32;
typedef __attribute__((ext_vector_type(8))) short bf16x8;   // MFMA A/B frag (4 VGPR)
typedef __attribute__((ext_vector_type(4))) float f32x4;    // MFMA C/D frag

__device__ __forceinline__ float bf_lo(uint32 u) { return __uint_as_float(u << 16); }
__device__ __forceinline__ float bf_hi(uint32 u) { return __uint_as_float(u & 0xffff0000u); }
// round-to-nearest-even f32 -> bf16 (no NaN inputs here)
__device__ __forceinline__ uint32 f2bf(float f) {
    uint32 u = __float_as_uint(f);
    return (u + 0x7fffu + ((u >> 16) & 1u)) >> 16;
}
__device__ __forceinline__ uint32 pack_bf2(float a, float b) {
    return f2bf(a) | (f2bf(b) << 16);
}

// ---------- init: bucket counts + attention vectors + MFMA B-fragments --------
// wgB: B-frags of Wg' (128x32), 8 frags = (T in 0..2 N-tiles)x(kt in 0..4 K-tiles);
//      element B[k][n]: n = 16T+(lane&15), k = kt*32+(lane>>4)*8+2*di{+1}.
//      W'[c][d] = Wg[(c&31)*128 + (c>>5)*32 + d].
// w2B: B-frags of W2 (32x64), 4 N-tiles, K=32 single tile.
__global__ __launch_bounds__(512) void k_init2(int* __restrict__ gcnt,
                                               const float* __restrict__ Wg,
                                               const float* __restrict__ ags,
                                               const float* __restrict__ agd,
                                               float* __restrict__ wals,
                                               float* __restrict__ wald,
                                               const float* __restrict__ W2,
                                               uint32* __restrict__ wgB,
                                               uint32* __restrict__ w2B) {
    int t = threadIdx.x;
    if (t < K_BUCKETS + 1) gcnt[t] = 0;
    if (t < 256) {
        int c = t & 127;
        int h = c >> 5, k = c & 31;
        const float* a = (t < 128) ? ags : agd;
        float acc = 0.f;
#pragma unroll
        for (int d = 0; d < 32; d++) acc += Wg[k * 128 + h * 32 + d] * a[h * 32 + d];
        if (t < 128) wals[c] = acc; else wald[c] = acc;
    }
    for (int i = t; i < 2048; i += 512) {
        int tile = i >> 8;            // 0..7 = T*4+kt
        int T = tile >> 2, kt = tile & 3;
        int r = i & 255;
        int L = r >> 2, di = r & 3;
        int k0 = kt * 32 + (L >> 4) * 8 + 2 * di;
        int k1 = k0 + 1;
        int n = T * 16 + (L & 15);
        float a = Wg[(k0 & 31) * 128 + (k0 >> 5) * 32 + n];
        float b = Wg[(k1 & 31) * 128 + (k1 >> 5) * 32 + n];
        wgB[i] = pack_bf2(a, b);
    }
    for (int i = t; i < 1024; i += 512) {
        int T = i >> 8;
        int r = i & 255;
        int L = r >> 2, di = r & 3;
        int k0 = (L >> 4) * 8 + 2 * di;
        int n = T * 16 + (L & 15);
        w2B[i] = pack_bf2(W2[k0 * 64 + n], W2[(k0 + 1) * 64 + n]);
    }
}

// ---------- CSR build via two-level bucket sort ----------

__global__ __launch_bounds__(256) void k_bcount(const int* __restrict__ ei,
                                                int* __restrict__ gcnt) {
    __shared__ int h[K_BUCKETS];
    int t = threadIdx.x;
    for (int i = t; i < K_BUCKETS; i += 256) h[i] = 0;
    __syncthreads();
    int base = blockIdx.x * 4096;
    int dd[16];
#pragma unroll
    for (int k = 0; k < 16; k++) {
        int e = base + k * 256 + t;
        dd[k] = (e < N_EDGES) ? ei[N_EDGES + e] : -1;
    }
#pragma unroll
    for (int k = 0; k < 16; k++)
        if (dd[k] >= 0) atomicAdd(&h[dd[k] >> 7], 1);
    __syncthreads();
    for (int i = t; i < K_BUCKETS; i += 256)
        if (h[i]) atomicAdd(&gcnt[i], h[i]);
}

__global__ __launch_bounds__(512) void k_bscan(const int* __restrict__ gcnt,
                                               int* __restrict__ gbase,
                                               int* __restrict__ gcursor) {
    __shared__ int sd[512];
    int t = threadIdx.x;
    int v = (t < K_BUCKETS) ? gcnt[t] : 0;
    sd[t] = v;
    __syncthreads();
    for (int off = 1; off < 512; off <<= 1) {
        int x = (t >= off) ? sd[t - off] : 0;
        __syncthreads();
        sd[t] += x;
        __syncthreads();
    }
    if (t < K_BUCKETS) {
        int excl = sd[t] - v;
        gbase[t] = excl;
        gcursor[t] = excl;
    }
    if (t == 0) gbase[K_BUCKETS] = sd[K_BUCKETS - 1];
}

__global__ __launch_bounds__(256) void k_bucket(const int* __restrict__ ei,
                                                int* __restrict__ gcursor,
                                                uint32* __restrict__ gpairs) {
    __shared__ int cnt[K_BUCKETS];
    __shared__ int bas[K_BUCKETS];
    int t = threadIdx.x;
    for (int i = t; i < K_BUCKETS; i += 256) cnt[i] = 0;
    __syncthreads();
    int base = blockIdx.x * 2048;
    int ss[8], dd[8], ml[8];
#pragma unroll
    for (int k = 0; k < 8; k++) {
        int e = base + k * 256 + t;
        ss[k] = (e < N_EDGES) ? ei[e] : -1;
        dd[k] = (e < N_EDGES) ? ei[N_EDGES + e] : 0;
    }
#pragma unroll
    for (int k = 0; k < 8; k++)
        if (ss[k] >= 0) ml[k] = atomicAdd(&cnt[dd[k] >> 7], 1);
    __syncthreads();
    for (int i = t; i < K_BUCKETS; i += 256)
        bas[i] = cnt[i] ? atomicAdd(&gcursor[i], cnt[i]) : 0;
    __syncthreads();
#pragma unroll
    for (int k = 0; k < 8; k++)
        if (ss[k] >= 0)
            gpairs[bas[dd[k] >> 7] + ml[k]] = ((uint32)ss[k] << 7) | (uint32)(dd[k] & 127);
}

__global__ __launch_bounds__(256) void k_node(const uint32* __restrict__ gpairs,
                                              const int* __restrict__ gbase,
                                              int* __restrict__ offs,
                                              float* __restrict__ dinv,
                                              int* __restrict__ srcs) {
    __shared__ int cnt[NPB];
    __shared__ int scn[NPB];
    __shared__ int cur[NPB];
    int t = threadIdx.x;
    int b = blockIdx.x;
    int lo = b << 7;
    int nn = N_NODES - lo; if (nn > NPB) nn = NPB;
    int pb = gbase[b], pe = gbase[b + 1];
    if (t < NPB) cnt[t] = 0;
    __syncthreads();
    for (int i = pb + t; i < pe; i += 256)
        atomicAdd(&cnt[gpairs[i] & 127], 1);
    __syncthreads();
    if (t < NPB) scn[t] = cnt[t];
    __syncthreads();
    for (int off = 1; off < NPB; off <<= 1) {
        int x = 0;
        if (t >= off && t < NPB) x = scn[t - off];
        __syncthreads();
        if (t < NPB) scn[t] += x;
        __syncthreads();
    }
    if (t < nn) {
        int excl = scn[t] - cnt[t];
        int o = pb + excl + lo + t;
        offs[lo + t] = o;
        cur[t] = o;
        dinv[lo + t] = rsqrtf((float)(cnt[t] + 1));
        srcs[pb + scn[t] + lo + t] = lo + t;   // self-loop at last slot
    }
    if (b == K_BUCKETS - 1 && t == 0) offs[N_NODES] = pe + N_NODES;
    __syncthreads();
    for (int i = pb + t; i < pe; i += 256) {
        uint32 u = gpairs[i];
        int pos = atomicAdd(&cur[u & 127], 1);
        srcs[pos] = (int)(u >> 7);
    }
}

// ---------- GCN1: xw1 = bf16( (x @ W1) * dinv[row] ), float2-LDS weights ------
__global__ __launch_bounds__(256) void k_gemm1(const float* __restrict__ x,
                                               const float* __restrict__ W1,
                                               const float* __restrict__ dinv,
                                               uint32* __restrict__ xw1) {
    __shared__ float wl[IN_C * HID];   // as float2[k2][f]
    __shared__ float xl[8 * IN_C];
    int t = threadIdx.x;
    for (int i = t; i < IN_C * HID; i += 256) {
        int k = i >> 5, f = i & 31;
        wl[(k >> 1) * 64 + f * 2 + (k & 1)] = W1[i];
    }
    int nb = blockIdx.x * 8;
    const float4* x4 = (const float4*)(x + (size_t)nb * IN_C);
    ((float4*)xl)[t] = x4[t];
    __syncthreads();
    int g = t >> 5, f = t & 31;
    const float2* xr = (const float2*)(xl + g * IN_C);
    const float2* wp = (const float2*)wl;
    float acc = 0.f;
#pragma unroll 16
    for (int k2 = 0; k2 < 64; k2++) {
        float2 xv = xr[k2];
        float2 wv = wp[k2 * 32 + f];
        acc += xv.x * wv.x + xv.y * wv.y;
    }
    float v = acc * dinv[nb + g];
    float vn = __shfl_xor(v, 1, 64);
    if ((f & 1) == 0) xw1[(size_t)(nb + g) * 16 + (f >> 1)] = pack_bf2(v, vn);
}

// ---------- GCN1 aggregate -> per-node 128B record ----------
// rec[n] (128B aligned): [0:16) e1s=exp(als_h), [16:32) e2s=exp(.2 als_h),
// [32:48) e1d, [48:64) e2d, [64:128) h1 as 16 packed-bf16 words.
__global__ __launch_bounds__(256) void k_gather1(const uint32* __restrict__ xw1,
                                                 const int* __restrict__ offs,
                                                 const int* __restrict__ srcs,
                                                 const float* __restrict__ dinv,
                                                 const float* __restrict__ b1,
                                                 const float* __restrict__ wals,
                                                 const float* __restrict__ wald,
                                                 char* __restrict__ rec) {
    int t = threadIdx.x;
    int l16 = t & 15;
    int n = blockIdx.x * 16 + (t >> 4);
    int s0 = offs[n], s1 = offs[n + 1];
    const char* xb = (const char*)xw1 + l16 * 4;
    float a0 = 0.f, a1 = 0.f, a2 = 0.f, a3 = 0.f;
    int j = s0;
    for (; j + 1 < s1; j += 2) {
        uint32 uA = *(const uint32*)(xb + ((uint32)srcs[j] << 6));
        uint32 uB = *(const uint32*)(xb + ((uint32)srcs[j + 1] << 6));
        a0 += bf_lo(uA); a1 += bf_hi(uA);
        a2 += bf_lo(uB); a3 += bf_hi(uB);
    }
    if (j < s1) {
        uint32 uA = *(const uint32*)(xb + ((uint32)srcs[j] << 6));
        a0 += bf_lo(uA); a1 += bf_hi(uA);
    }
    float dn = dinv[n];
    float2 b = ((const float2*)b1)[l16];
    float vx = (a0 + a2) * dn + b.x;
    float vy = (a1 + a3) * dn + b.y;
    vx = vx > 0.f ? vx : 0.f;
    vy = vy > 0.f ? vy : 0.f;
    char* rn = rec + (size_t)n * 128;
    *(uint32*)(rn + 64 + l16 * 4) = pack_bf2(vx, vy);

    float ps0, ps1, ps2, ps3, pd0, pd1, pd2, pd3;
    {
        float2 w0 = ((const float2*)wals)[0 * 16 + l16];
        float2 w1 = ((const float2*)wals)[1 * 16 + l16];
        float2 w2 = ((const float2*)wals)[2 * 16 + l16];
        float2 w3 = ((const float2*)wals)[3 * 16 + l16];
        ps0 = vx * w0.x + vy * w0.y;
        ps1 = vx * w1.x + vy * w1.y;
        ps2 = vx * w2.x + vy * w2.y;
        ps3 = vx * w3.x + vy * w3.y;
        float2 u0 = ((const float2*)wald)[0 * 16 + l16];
        float2 u1 = ((const float2*)wald)[1 * 16 + l16];
        float2 u2 = ((const float2*)wald)[2 * 16 + l16];
        float2 u3 = ((const float2*)wald)[3 * 16 + l16];
        pd0 = vx * u0.x + vy * u0.y;
        pd1 = vx * u1.x + vy * u1.y;
        pd2 = vx * u2.x + vy * u2.y;
        pd3 = vx * u3.x + vy * u3.y;
    }
#pragma unroll
    for (int m = 1; m < 16; m <<= 1) {
        ps0 += __shfl_xor(ps0, m, 16); ps1 += __shfl_xor(ps1, m, 16);
        ps2 += __shfl_xor(ps2, m, 16); ps3 += __shfl_xor(ps3, m, 16);
        pd0 += __shfl_xor(pd0, m, 16); pd1 += __shfl_xor(pd1, m, 16);
        pd2 += __shfl_xor(pd2, m, 16); pd3 += __shfl_xor(pd3, m, 16);
    }
    if (l16 == 0) {
        float4* r4 = (float4*)rn;
        r4[0] = make_float4(__expf(ps0), __expf(ps1), __expf(ps2), __expf(ps3));
        r4[1] = make_float4(__expf(NEG_SLOPE * ps0), __expf(NEG_SLOPE * ps1),
                            __expf(NEG_SLOPE * ps2), __expf(NEG_SLOPE * ps3));
        r4[2] = make_float4(__expf(pd0), __expf(pd1), __expf(pd2), __expf(pd3));
        r4[3] = make_float4(__expf(NEG_SLOPE * pd0), __expf(NEG_SLOPE * pd1),
                            __expf(NEG_SLOPE * pd2), __expf(NEG_SLOPE * pd3));
    }
}

// ---------- Fused GAT: record edge aggregate + MFMA 128->32 post-GEMM ---------
// 512 threads = 16 nodes x 32 lanes. Edge loop as R12. After barrier, wave 0
// does the whole 16-node 128->32 GEMM with 8 x mfma_f32_16x16x32_bf16:
// A[m=lane&15][k=quad*8+j] read as uint4 from gl rows; B-frags precomputed.
__global__ __launch_bounds__(512) void k_gat_agg(const char* __restrict__ rec,
                                                 const int* __restrict__ offs,
                                                 const int* __restrict__ srcs,
                                                 const uint32* __restrict__ wgB,
                                                 const float* __restrict__ bg,
                                                 const float* __restrict__ dinv,
                                                 uint32* __restrict__ h2s) {
    __shared__ __align__(16) uint32 gl[16][64];  // packed g per node: 4 KB
    int t = threadIdx.x;
    int l32 = t & 31;
    int g8 = t >> 5;             // node slot 0..15
    int n = blockIdx.x * 16 + g8;
    int l16 = l32 & 15;
    int par = l32 >> 4;          // edge parity this lane gathers
    int s0 = offs[n], s1 = offs[n + 1];
    const float4* dn4 = (const float4*)(rec + (size_t)n * 128);
    float4 d1 = dn4[2];          // e1d
    float4 d2 = dn4[3];          // e2d
    uint32 hoff = 64 + l16 * 4;  // lane's h1 word offset within record

    float g00 = 0.f, g01 = 0.f, g10 = 0.f, g11 = 0.f;
    float g20 = 0.f, g21 = 0.f, g30 = 0.f, g31 = 0.f;
    float ss0 = 0.f, ss1 = 0.f, ss2 = 0.f, ss3 = 0.f;

#define GAT_EDGE(J)                                                            \
    {                                                                          \
        uint32 off = (uint32)srcs[J] << 7;                                     \
        float4 e1 = *(const float4*)(rec + off);                               \
        float4 e2 = *(const float4*)(rec + off + 16);                          \
        uint32 u = *(const uint32*)(rec + off + hoff);                         \
        float flo = bf_lo(u), fhi = bf_hi(u);                                  \
        float p, q, w;                                                         \
        p = e1.x * d1.x; q = e2.x * d2.x; w = p > 1.f ? p : q;                 \
        ss0 += w; g00 += w * flo; g01 += w * fhi;                              \
        p = e1.y * d1.y; q = e2.y * d2.y; w = p > 1.f ? p : q;                 \
        ss1 += w; g10 += w * flo; g11 += w * fhi;                              \
        p = e1.z * d1.z; q = e2.z * d2.z; w = p > 1.f ? p : q;                 \
        ss2 += w; g20 += w * flo; g21 += w * fhi;                              \
        p = e1.w * d1.w; q = e2.w * d2.w; w = p > 1.f ? p : q;                 \
        ss3 += w; g30 += w * flo; g31 += w * fhi;                              \
    }

    int j = s0 + par;
    for (; j + 2 < s1; j += 4) {   // unroll 2 for MLP
        GAT_EDGE(j);
        GAT_EDGE(j + 2);
    }
    if (j < s1) GAT_EDGE(j);
#undef GAT_EDGE

    // combine edge-parity halves (lanes l32 ^ 16)
    ss0 += __shfl_xor(ss0, 16, 64); ss1 += __shfl_xor(ss1, 16, 64);
    ss2 += __shfl_xor(ss2, 16, 64); ss3 += __shfl_xor(ss3, 16, 64);
    g00 += __shfl_xor(g00, 16, 64); g01 += __shfl_xor(g01, 16, 64);
    g10 += __shfl_xor(g10, 16, 64); g11 += __shfl_xor(g11, 16, 64);
    g20 += __shfl_xor(g20, 16, 64); g21 += __shfl_xor(g21, 16, 64);
    g30 += __shfl_xor(g30, 16, 64); g31 += __shfl_xor(g31, 16, 64);
    float i0 = 0.25f / ss0, i1 = 0.25f / ss1, i2 = 0.25f / ss2, i3 = 0.25f / ss3;
    if (l32 < 16) {
        gl[g8][0 * 16 + l16] = pack_bf2(g00 * i0, g01 * i0);
        gl[g8][1 * 16 + l16] = pack_bf2(g10 * i1, g11 * i1);
        gl[g8][2 * 16 + l16] = pack_bf2(g20 * i2, g21 * i2);
        gl[g8][3 * 16 + l16] = pack_bf2(g30 * i3, g31 * i3);
    }
    __syncthreads();
    if (t < 64) {
        int L = t;
        int mA = L & 15;          // A-operand row (node) for this lane
        int quad = L >> 4;
        int nbase = blockIdx.x * 16;
        float dn0 = dinv[nbase + quad * 4 + 0];
        float dn1 = dinv[nbase + quad * 4 + 1];
        float dn2 = dinv[nbase + quad * 4 + 2];
        float dn3 = dinv[nbase + quad * 4 + 3];
#pragma unroll
        for (int T = 0; T < 2; T++) {
            f32x4 acc = {0.f, 0.f, 0.f, 0.f};
#pragma unroll
            for (int kt = 0; kt < 4; kt++) {
                bf16x8 af = *(const bf16x8*)&gl[mA][kt * 16 + quad * 4];
                bf16x8 bf = *(const bf16x8*)(wgB + (size_t)((T * 4 + kt) * 64 + L) * 4);
                acc = __builtin_amdgcn_mfma_f32_16x16x32_bf16(af, bf, acc, 0, 0, 0);
            }
            int d = T * 16 + (L & 15);    // D col = lane&15 (output channel)
            float bgd = bg[d];
            float dns[4] = {dn0, dn1, dn2, dn3};
#pragma unroll
            for (int r = 0; r < 4; r++) {
                int node = nbase + quad * 4 + r;   // D row = quad*4+reg
                float v = acc[r] + bgd;
                v = v > 0.f ? v : 0.f;
                v *= dns[r];
                float vn = __shfl_xor(v, 1, 64);
                if ((d & 1) == 0)
                    h2s[(size_t)node * 16 + (d >> 1)] = pack_bf2(v, vn);
            }
        }
    }
}

// ---------- Fused GCN2: edge aggregate + MFMA 32->64 output GEMM --------------
// 256 threads = 16 nodes x 16 lanes; wave 0 does the 16-node GEMM (4 MFMAs).
__global__ __launch_bounds__(256) void k_gather2(const uint32* __restrict__ h2s,
                                                 const int* __restrict__ offs,
                                                 const int* __restrict__ srcs,
                                                 const uint32* __restrict__ w2B,
                                                 const float* __restrict__ dinv,
                                                 const float* __restrict__ b2,
                                                 float* __restrict__ out) {
    __shared__ __align__(16) uint32 gbf[16][16]; // packed g2: 1 KB
    int t = threadIdx.x;
    int l16 = t & 15;
    int g16 = t >> 4;
    int n = blockIdx.x * 16 + g16;
    int s0 = offs[n], s1 = offs[n + 1];
    const char* xb = (const char*)h2s + l16 * 4;
    float a0 = 0.f, a1 = 0.f, a2 = 0.f, a3 = 0.f;
    int j = s0;
    for (; j + 1 < s1; j += 2) {
        uint32 uA = *(const uint32*)(xb + ((uint32)srcs[j] << 6));
        uint32 uB = *(const uint32*)(xb + ((uint32)srcs[j + 1] << 6));
        a0 += bf_lo(uA); a1 += bf_hi(uA);
        a2 += bf_lo(uB); a3 += bf_hi(uB);
    }
    if (j < s1) {
        uint32 uA = *(const uint32*)(xb + ((uint32)srcs[j] << 6));
        a0 += bf_lo(uA); a1 += bf_hi(uA);
    }
    gbf[g16][l16] = pack_bf2(a0 + a2, a1 + a3);
    __syncthreads();
    if (t < 64) {
        int L = t;
        int quad = L >> 4;
        int nbase = blockIdx.x * 16;
        float dns[4];
#pragma unroll
        for (int r = 0; r < 4; r++) dns[r] = dinv[nbase + quad * 4 + r];
        bf16x8 af = *(const bf16x8*)&gbf[L & 15][quad * 4];
#pragma unroll
        for (int T = 0; T < 4; T++) {
            bf16x8 bf = *(const bf16x8*)(w2B + (size_t)(T * 64 + L) * 4);
            f32x4 acc = {0.f, 0.f, 0.f, 0.f};
            acc = __builtin_amdgcn_mfma_f32_16x16x32_bf16(af, bf, acc, 0, 0, 0);
            int d = T * 16 + (L & 15);
            float b2d = b2[d];
#pragma unroll
            for (int r = 0; r < 4; r++) {
                int node = nbase + quad * 4 + r;
                out[(size_t)node * OUT_C + d] = acc[r] * dns[r] + b2d;
            }
        }
    }
}

extern "C" void kernel_launch(void* const* d_in, const int* in_sizes, int n_in,
                              void* d_out, int out_size, void* d_ws, size_t ws_size,
                              hipStream_t stream) {
    const float* x   = (const float*)d_in[0];
    const int*   ei  = (const int*)d_in[1];   // int64 in reference -> int32 from harness
    const float* W1  = (const float*)d_in[2];
    const float* b1  = (const float*)d_in[3];
    const float* Wg  = (const float*)d_in[4];
    const float* ags = (const float*)d_in[5];
    const float* agd = (const float*)d_in[6];
    const float* bg  = (const float*)d_in[7];
    const float* W2  = (const float*)d_in[8];
    const float* b2  = (const float*)d_in[9];
    float* out = (float*)d_out;

    char* p = (char*)d_ws;
    auto alloc = [&](size_t bytes) -> void* {
        void* r = (void*)p;
        p += (bytes + 255) & ~(size_t)255;
        return r;
    };
    float*  dinv    = (float*)alloc((size_t)N_NODES * 4);
    int*    offs    = (int*)  alloc((size_t)(N_NODES + 1) * 4);
    int*    gcnt    = (int*)  alloc((size_t)(K_BUCKETS + 1) * 4);
    int*    gbase   = (int*)  alloc((size_t)(K_BUCKETS + 1) * 4);
    int*    gcursor = (int*)  alloc((size_t)(K_BUCKETS + 1) * 4);
    int*    srcs    = (int*)  alloc((size_t)EP * 4);
    uint32* gpairs  = (uint32*)alloc((size_t)N_EDGES * 4);
    uint32* xw1     = (uint32*)alloc((size_t)N_NODES * 16 * 4);
    char*   rec     = (char*) alloc((size_t)N_NODES * 128);
    float*  wals    = (float*)alloc(128 * 4);
    float*  wald    = (float*)alloc(128 * 4);
    uint32* wgB     = (uint32*)alloc(2048 * 4);
    uint32* w2B     = (uint32*)alloc(1024 * 4);
    uint32* h2s     = (uint32*)alloc((size_t)N_NODES * 16 * 4);

    // init + CSR build (two-level bucket sort)
    k_init2<<<1, 512, 0, stream>>>(gcnt, Wg, ags, agd, wals, wald, W2, wgB, w2B);
    k_bcount<<<(N_EDGES + 4095) / 4096, 256, 0, stream>>>(ei, gcnt);
    k_bscan<<<1, 512, 0, stream>>>(gcnt, gbase, gcursor);
    k_bucket<<<(N_EDGES + 2047) / 2048, 256, 0, stream>>>(ei, gcursor, gpairs);
    k_node<<<K_BUCKETS, 256, 0, stream>>>(gpairs, gbase, offs, dinv, srcs);

    // GCN1
    k_gemm1<<<N_NODES / 8, 256, 0, stream>>>(x, W1, dinv, xw1);
    k_gather1<<<N_NODES / 16, 256, 0, stream>>>(xw1, offs, srcs, dinv, b1,
                                                wals, wald, rec);

    // GAT: record edge aggregate + MFMA post-GEMM
    k_gat_agg<<<N_NODES / 16, 512, 0, stream>>>(rec, offs, srcs, wgB, bg, dinv, h2s);

    // GCN2: edge aggregate + MFMA output GEMM
    k_gather2<<<N_NODES / 16, 256, 0, stream>>>(h2s, offs, srcs, w2B, dinv, b2, out);
}